// Round 9
// baseline (277.568 us; speedup 1.0000x reference)
//
#include <hip/hip_runtime.h>

#define DEVI __device__ __forceinline__

typedef __attribute__((ext_vector_type(8))) short short8;
typedef __attribute__((ext_vector_type(4))) float f32x4;
typedef unsigned short u16;

DEVI u16 f2bf(float f){
  unsigned int u = __float_as_uint(f);
  unsigned int r = (u + 0x7FFFu + ((u>>16)&1u)) >> 16;
  return (u16)r;
}
DEVI float bf2f(u16 h){ return __uint_as_float(((unsigned int)h)<<16); }

DEVI unsigned int cvt_pk_bf16(float a, float b){
  unsigned int r;
  asm("v_cvt_pk_bf16_f32 %0, %1, %2" : "=v"(r) : "v"(a), "v"(b));
  return r;   // lo = bf16(a), hi = bf16(b)
}

DEVI float gelu_f(float x){
  float x3 = x*x*x;
  float t = tanhf(0.7978845608028654f*(x + 0.044715f*x3));
  return 0.5f*x*(1.0f + t);
}

DEVI void async_cp16(const void* g, void* l){
  __builtin_amdgcn_global_load_lds(
      (const __attribute__((address_space(1))) unsigned int*)g,
      (__attribute__((address_space(3))) unsigned int*)l, 16, 0, 0);
}

// ---------------- weight transpose + bf16 convert: w (K x N) f32 -> wt (N x K) bf16
__global__ __launch_bounds__(256) void wtrans_k(const float* __restrict__ w,
                                                u16* __restrict__ wt, int K, int N){
  __shared__ float tile[32][33];
  int tn = blockIdx.x*32, tk = blockIdx.y*32;
  int r = threadIdx.x>>3, c4 = (threadIdx.x&7)*4;
  float4 vv = *(const float4*)&w[(size_t)(tk+r)*N + tn + c4];
  tile[r][c4+0]=vv.x; tile[r][c4+1]=vv.y; tile[r][c4+2]=vv.z; tile[r][c4+3]=vv.w;
  __syncthreads();
  u16 o[4];
  #pragma unroll
  for (int j=0;j<4;j++) o[j] = f2bf(tile[c4+j][r]);
  unsigned long long pk = (unsigned long long)o[0] | ((unsigned long long)o[1]<<16)
                        | ((unsigned long long)o[2]<<32) | ((unsigned long long)o[3]<<48);
  *(unsigned long long*)&wt[(size_t)(tn+r)*K + tk + c4] = pk;
}

// ---------------- LN1: x f32 (4096x768) -> xin bf16
__global__ __launch_bounds__(256) void ln1_k(const float* __restrict__ x,
                                             const float* __restrict__ sc,
                                             u16* __restrict__ xin){
  int row = blockIdx.x, tid = threadIdx.x;
  const float* xr = x + (size_t)row*768;
  float v[3]; float s=0.f, ss=0.f;
  #pragma unroll
  for (int i=0;i<3;i++){ v[i]=xr[tid+i*256]; s+=v[i]; ss+=v[i]*v[i]; }
  #pragma unroll
  for (int m=1;m<=32;m<<=1){ s += __shfl_xor(s,m,64); ss += __shfl_xor(ss,m,64); }
  __shared__ float ls0[4], ls1_[4];
  int w = tid>>6;
  if ((tid&63)==0){ ls0[w]=s; ls1_[w]=ss; }
  __syncthreads();
  s = ls0[0]+ls0[1]+ls0[2]+ls0[3]; ss = ls1_[0]+ls1_[1]+ls1_[2]+ls1_[3];
  float mu = s*(1.f/768.f);
  float var = ss*(1.f/768.f) - mu*mu;
  float inv = rsqrtf(var + 1e-6f);
  #pragma unroll
  for (int i=0;i<3;i++){ int c=tid+i*256; xin[(size_t)row*768+c] = f2bf((v[i]-mu)*inv*sc[c]); }
}

// ---------------- GEMM: C(MxN) = A(MxK,bf16) * Bt(NxK,bf16)^T
// EPI 0: f32 partial plane (split-K)   EPI 2: bf16(gelu(acc+bias))   EPI 3: plain bf16
template<int EPI, int SPLITK>
__global__ __launch_bounds__(256) void gemm_k(
    const u16* __restrict__ A, const u16* __restrict__ Bt,
    int M, int N, int K,
    float* __restrict__ Cf, u16* __restrict__ Cb,
    const float* __restrict__ bias)
{
  __shared__ __align__(16) u16 Al[128*32];
  __shared__ __align__(16) u16 Bl[128*32];
  const int tid = threadIdx.x, w = tid>>6, l = tid&63;
  const int m0 = blockIdx.y*128, n0 = blockIdx.x*128;
  const int Ksub = K/SPLITK;
  const int kc = (SPLITK>1) ? blockIdx.z : 0;
  const int kbase = kc*Ksub;
  const int wr = (w>>1)*64, wc = (w&1)*64;
  f32x4 acc[4][4];
  #pragma unroll
  for (int i=0;i<4;i++)
    #pragma unroll
    for (int j=0;j<4;j++){ f32x4 z={0.f,0.f,0.f,0.f}; acc[i][j]=z; }
  const int lr = l>>2, lc = l&3;
  for (int k0=0; k0<Ksub; k0+=32){
    __syncthreads();
    #pragma unroll
    for (int it=0; it<2; ++it){
      int arow = w*32 + it*16;
      async_cp16(A  + (size_t)(m0+arow+lr)*K + kbase + k0 + lc*8, &Al[arow*32]);
      async_cp16(Bt + (size_t)(n0+arow+lr)*K + kbase + k0 + lc*8, &Bl[arow*32]);
    }
    __syncthreads();
    short8 af[4], bfr[4];
    #pragma unroll
    for (int mi=0;mi<4;++mi) af[mi]  = *(const short8*)&Al[(wr+mi*16+(l&15))*32 + (l>>4)*8];
    #pragma unroll
    for (int ni=0;ni<4;++ni) bfr[ni] = *(const short8*)&Bl[(wc+ni*16+(l&15))*32 + (l>>4)*8];
    #pragma unroll
    for (int mi=0;mi<4;++mi)
      #pragma unroll
      for (int ni=0;ni<4;++ni)
        acc[mi][ni] = __builtin_amdgcn_mfma_f32_16x16x32_bf16(af[mi], bfr[ni], acc[mi][ni], 0,0,0);
  }
  #pragma unroll
  for (int mi=0;mi<4;++mi){
    int rb = m0 + wr + mi*16 + ((l>>4)<<2);
    #pragma unroll
    for (int ni=0;ni<4;++ni){
      int col = n0 + wc + ni*16 + (l&15);
      #pragma unroll
      for (int r=0;r<4;r++){
        int row = rb + r;
        float v = acc[mi][ni][r];
        if (EPI==0)      Cf[((size_t)kc*M + row)*N + col] = v;
        else if (EPI==2) Cb[(size_t)row*N+col] = f2bf(gelu_f(v + bias[col]));
        else             Cb[(size_t)row*N+col] = f2bf(v);
      }
    }
  }
}

// ---------------- split-K reduce + bias/ls/resid + LN2 + gelu (out-proj path)
__global__ __launch_bounds__(256) void redln_k(
    const float* __restrict__ P, const float* __restrict__ bias,
    const float* __restrict__ lsc, const float* __restrict__ resid,
    const float* __restrict__ ln2sc, const float* __restrict__ ln2bi,
    float* __restrict__ x0, u16* __restrict__ x1)
{
  const size_t MN = 4096ull*768;
  int row = blockIdx.x, tid = threadIdx.x;
  float v[3]; float s=0.f, ss=0.f;
  #pragma unroll
  for (int i=0;i<3;i++){
    int c = tid + i*256;
    size_t idx = (size_t)row*768 + c;
    float acc = P[idx] + P[MN+idx] + P[2*MN+idx] + P[3*MN+idx];
    float y = lsc[c]*(acc + bias[c]) + resid[idx];
    x0[idx] = y;
    v[i] = y; s += y; ss += y*y;
  }
  #pragma unroll
  for (int m=1;m<=32;m<<=1){ s += __shfl_xor(s,m,64); ss += __shfl_xor(ss,m,64); }
  __shared__ float ls0[4], ls1_[4];
  int w = tid>>6;
  if ((tid&63)==0){ ls0[w]=s; ls1_[w]=ss; }
  __syncthreads();
  s = ls0[0]+ls0[1]+ls0[2]+ls0[3]; ss = ls1_[0]+ls1_[1]+ls1_[2]+ls1_[3];
  float mu = s*(1.f/768.f);
  float var = ss*(1.f/768.f) - mu*mu;
  float inv = rsqrtf(var + 1e-6f);
  #pragma unroll
  for (int i=0;i<3;i++){
    int c = tid + i*256;
    float y = (v[i]-mu)*inv*ln2sc[c] + ln2bi[c];
    x1[(size_t)row*768 + c] = f2bf(gelu_f(y));
  }
}

// ---------------- split-K reduce + bias/ls/resid (final output)
__global__ __launch_bounds__(256) void red_k(
    const float* __restrict__ P, const float* __restrict__ bias,
    const float* __restrict__ lsc, const float* __restrict__ resid,
    float* __restrict__ out)
{
  const size_t MN = 4096ull*768;
  size_t i = ((size_t)blockIdx.x*256 + threadIdx.x)*4;
  int c = (int)(i % 768);
  float4 a0 = *(const float4*)&P[i];
  float4 a1 = *(const float4*)&P[MN+i];
  float4 a2 = *(const float4*)&P[2*MN+i];
  float4 a3 = *(const float4*)&P[3*MN+i];
  float4 bi = *(const float4*)&bias[c];
  float4 ls = *(const float4*)&lsc[c];
  float4 rs = *(const float4*)&resid[i];
  float4 o;
  o.x = ls.x*(a0.x+a1.x+a2.x+a3.x + bi.x) + rs.x;
  o.y = ls.y*(a0.y+a1.y+a2.y+a3.y + bi.y) + rs.y;
  o.z = ls.z*(a0.z+a1.z+a2.z+a3.z + bi.z) + rs.z;
  o.w = ls.w*(a0.w+a1.w+a2.w+a3.w + bi.w) + rs.w;
  *(float4*)&out[i] = o;
}

// ---------------- qkv postprocess v2: tile kernel, rms+rope in-register,
// V transposed through padded LDS so ALL global writes are coalesced.
__global__ __launch_bounds__(256) void postproc2_k(
  const u16* __restrict__ qkv, const float* __restrict__ sincos,
  const float* __restrict__ aq, const float* __restrict__ ak,
  const float* __restrict__ aqs, const float* __restrict__ aks,
  u16* __restrict__ qg, u16* __restrict__ kg, u16* __restrict__ vg,
  u16* __restrict__ qsg, u16* __restrict__ ksg, u16* __restrict__ vsg)
{
  __shared__ u16 vt[2][64*66];   // [t][d] padded: row stride 66 u16 (132 B)
  const int bid = blockIdx.x;
  const int b = bid/384; int r0 = bid - b*384;
  const int v = r0/96;   int r1 = r0 - v*96;
  const int t6 = r1/12;  const int h = r1 - t6*12;
  const int T0 = t6*64;
  const int tid = threadIdx.x, w = tid>>6, l = tid&63;
  const int tq = l>>4, dq = l&15;
  const int m0 = b*2048 + v*512;
  const size_t gQbase = ((size_t)(b*12) + h)*2048 + v*512;
  const size_t sQbase = ((size_t)((v*2+b)*12) + h)*512;

  // ---- q / k / qs / ks: rms + rope, row-coalesced writes
  #pragma unroll
  for (int qi=0; qi<4; ++qi){
    const int tt = (qi<2) ? qi : qi+1;          // 0,1,3,4
    const float* al = (qi==0)?aq:(qi==1)?ak:(qi==2)?aqs:aks;
    float4 alv = *(const float4*)&al[h*64 + dq*4];
    u16* dst = (qi==0)?qg:(qi==1)?kg:(qi==2)?qsg:ksg;
    const size_t obase = (qi<2) ? gQbase : sQbase;
    #pragma unroll
    for (int it=0; it<4; ++it){
      const int t = T0 + w*16 + it*4 + tq;
      const u16* src = &qkv[(size_t)(m0+t)*4608 + tt*768 + h*64 + dq*4];
      ushort2 u01 = *(const ushort2*)src;
      ushort2 u23 = *(const ushort2*)(src+2);
      float x0=bf2f(u01.x), x1=bf2f(u01.y), x2=bf2f(u23.x), x3=bf2f(u23.y);
      float ss = x0*x0+x1*x1+x2*x2+x3*x3;
      #pragma unroll
      for (int mm=1;mm<=8;mm<<=1) ss += __shfl_xor(ss,mm,64);
      float rinv = rsqrtf(ss*(1.f/64.f) + 1e-5f);
      x0 *= alv.x*rinv; x1 *= alv.y*rinv; x2 *= alv.z*rinv; x3 *= alv.w*rinv;
      float4 cs01 = *(const float4*)&sincos[(size_t)(t*64 + dq*4)*2];
      float4 cs23 = *(const float4*)&sincos[(size_t)(t*64 + dq*4)*2 + 4];
      float y0 = x0*cs01.x - x1*cs01.y;
      float y1 = x1*cs01.z + x0*cs01.w;
      float y2 = x2*cs23.x - x3*cs23.y;
      float y3 = x3*cs23.z + x2*cs23.w;
      unsigned int lo = cvt_pk_bf16(y0, y1);
      unsigned int hi = cvt_pk_bf16(y2, y3);
      unsigned int* po = (unsigned int*)&dst[(obase + t)*64 + dq*4];
      po[0] = lo; po[1] = hi;
    }
  }

  // ---- v / vs: stage [t][d] tiles in LDS, write transposed [d][t] coalesced
  #pragma unroll
  for (int vi=0; vi<2; ++vi){
    const int tt = (vi==0) ? 2 : 5;
    #pragma unroll
    for (int it=0; it<4; ++it){
      const int t = T0 + w*16 + it*4 + tq;
      const int tl = w*16 + it*4 + tq;
      const u16* src = &qkv[(size_t)(m0+t)*4608 + tt*768 + h*64 + dq*4];
      ushort2 u01 = *(const ushort2*)src;
      ushort2 u23 = *(const ushort2*)(src+2);
      unsigned int* pl = (unsigned int*)&vt[vi][tl*66 + dq*4];
      pl[0] = (unsigned int)u01.x | ((unsigned int)u01.y<<16);
      pl[1] = (unsigned int)u23.x | ((unsigned int)u23.y<<16);
    }
  }
  __syncthreads();
  {
    const size_t vgb = (((size_t)(b*12) + h)*64)*2048 + v*512 + T0 + l;
    #pragma unroll
    for (int i=0;i<16;++i){
      int d = w*16 + i;
      vg[vgb + (size_t)d*2048] = vt[0][l*66 + d];
    }
    const size_t vsb = (((size_t)((v*2+b)*12) + h)*64)*512 + T0 + l;
    #pragma unroll
    for (int i=0;i<16;++i){
      int d = w*16 + i;
      vsg[vsb + (size_t)d*512] = vt[1][l*66 + d];
    }
  }
}

// ---------------- merged segment-masked flash attention, QBLK=64, 1536 blocks
// Q/K: [seq][h][L][64] bf16 ; Vt: [seq][h][64][L] bf16 ; Out bf16 [4096][1536]
// Direct exp (|s|<=8, rms-norm'd q/k). Single-buffered K/V LDS (~25KB).
// __launch_bounds__(256,4): 128-VGPR budget so the kr/vr prefetch + ao/qf
// state stays in registers (R8's 64-VGPR allocation spilled -> 100MB scratch
// writes). Next tile's loads issued into regs BEFORE compute. Coalesced epi.
__global__ __launch_bounds__(256, 4) void attn6_k(
  const u16* __restrict__ Qg, const u16* __restrict__ Kg, const u16* __restrict__ Vtg,
  const u16* __restrict__ Qs, const u16* __restrict__ Ks, const u16* __restrict__ Vts,
  u16* __restrict__ Out, const int* __restrict__ pids)
{
  __shared__ __align__(16) u16 Kl[64*64];
  __shared__ __align__(16) u16 Vl[64*64];
  __shared__ __align__(16) u16 Pl[4][16*64];
  __shared__ unsigned long long amask_s;
  const int gid = blockIdx.x;
  // balanced XCD swizzle: each XCD gets 96 global + 96 shifted contiguous blocks
  const int xcd = gid & 7, idx = gid >> 3;
  const int lid = (idx < 96) ? xcd*96 + idx : 768 + xcd*96 + (idx - 96);
  const int tid = threadIdx.x, w = tid>>6, l = tid&63;
  const u16 *Q, *K, *Vt; const int* prow;
  int L, seq, h, qb, orow0, ocol;
  if (lid < 768){
    seq = lid/384; int rem2 = lid - seq*384; h = rem2>>5; qb = rem2&31;
    Q=Qg; K=Kg; Vt=Vtg; L=2048;
    prow = pids + seq*512; orow0 = seq*2048; ocol = h*64;
  } else {
    int g2 = lid - 768; seq = g2/96; int rem2 = g2 - seq*96; h = rem2>>3; qb = rem2&7;
    Q=Qs; K=Ks; Vt=Vts; L=512;
    prow = pids + (seq&1)*512; orow0 = (seq&1)*2048 + (seq>>1)*512; ocol = 768 + h*64;
  }
  const size_t base = ((size_t)(seq*12) + h)*(size_t)L*64;
  const int q0 = qb*64, tq0 = q0 & 511;
  short8 qf[2];
  const int qrow = q0 + w*16 + (l&15);
  #pragma unroll
  for (int s=0;s<2;s++) qf[s] = *(const short8*)&Q[base + (size_t)qrow*64 + s*32 + (l>>4)*8];
  const int qlo = prow[tq0], qhi = prow[tq0+63];
  int sq[4];
  #pragma unroll
  for (int r=0;r<4;r++) sq[r] = prow[tq0 + w*16 + (l>>4)*4 + r];
  float lsum[4]; f32x4 ao[4];
  #pragma unroll
  for (int r=0;r<4;r++) lsum[r]=0.f;
  #pragma unroll
  for (int d=0;d<4;d++){ f32x4 z={0.f,0.f,0.f,0.f}; ao[d]=z; }
  const int nk = L/64;
  // ---- active-tile bitmask (uniform): wave 0 ballots over segment ranges
  bool act = false;
  if (tid < 64 && tid < nk){
    int tk0 = (tid*64)&511;
    act = (prow[tk0+63] >= qlo) && (prow[tk0] <= qhi);
  }
  unsigned long long bm = __ballot(act);
  if (tid==0) amask_s = bm;
  __syncthreads();
  unsigned long long rem = amask_s;   // non-empty: diagonal tile always active
  int t = (int)(__ffsll((unsigned long long)rem)-1); rem &= rem-1;
  uint4 kr[2], vr[2];
  {  // prologue: stage first tile
    int k0 = t*64;
    #pragma unroll
    for (int it=0;it<2;++it){
      int slot=it*256+tid, row=slot>>3, c16=slot&7;
      kr[it] = *(const uint4*)&K[base + (size_t)(k0+row)*64 + c16*8];
      vr[it] = *(const uint4*)&Vt[base + (size_t)row*(size_t)L + k0 + c16*8];
    }
    #pragma unroll
    for (int it=0;it<2;++it){
      int slot=it*256+tid, row=slot>>3, c16=slot&7;
      int boff = row*128 + ((c16*16) ^ ((row&7)<<4));
      *(uint4*)((char*)&Kl[0] + boff) = kr[it];
      *(uint4*)((char*)&Vl[0] + boff) = vr[it];
    }
  }
  __syncthreads();
  while (true){
    int tn = rem ? (int)(__ffsll((unsigned long long)rem)-1) : -1;
    if (tn >= 0){           // issue next tile's loads now; they land during compute
      rem &= rem-1;
      int k0n = tn*64;
      #pragma unroll
      for (int it=0;it<2;++it){
        int slot=it*256+tid, row=slot>>3, c16=slot&7;
        kr[it] = *(const uint4*)&K[base + (size_t)(k0n+row)*64 + c16*8];
        vr[it] = *(const uint4*)&Vt[base + (size_t)row*(size_t)L + k0n + c16*8];
      }
    }
    // ---- compute current tile from LDS
    const int tk0 = (t*64) & 511;
    int skv[4];
    #pragma unroll
    for (int kb=0;kb<4;kb++) skv[kb] = prow[tk0 + kb*16 + (l&15)];
    // ---- QK^T
    f32x4 s4[4];
    #pragma unroll
    for (int kb=0;kb<4;kb++){
      const int krow = kb*16 + (l&15);
      f32x4 a = {0.f,0.f,0.f,0.f};
      #pragma unroll
      for (int s=0;s<2;s++){
        int boff = krow*128 + ((s*64 + (l>>4)*16) ^ ((krow&7)<<4));
        short8 kf = *(const short8*)((const char*)&Kl[0] + boff);
        a = __builtin_amdgcn_mfma_f32_16x16x32_bf16(qf[s], kf, a, 0,0,0);
      }
      s4[kb] = a;
    }
    // ---- mask + direct exp + P relayout (cvt_pk pairs)
    #pragma unroll
    for (int kb=0;kb<4;kb++){
      float p0 = (skv[kb] == sq[0]) ? __expf(s4[kb][0]*0.125f) : 0.f;
      float p1 = (skv[kb] == sq[1]) ? __expf(s4[kb][1]*0.125f) : 0.f;
      float p2 = (skv[kb] == sq[2]) ? __expf(s4[kb][2]*0.125f) : 0.f;
      float p3 = (skv[kb] == sq[3]) ? __expf(s4[kb][3]*0.125f) : 0.f;
      lsum[0]+=p0; lsum[1]+=p1; lsum[2]+=p2; lsum[3]+=p3;
      unsigned int u01 = cvt_pk_bf16(p0, p1);
      unsigned int u23 = cvt_pk_bf16(p2, p3);
      int prw0 = (l>>4)*4;
      Pl[w][(prw0+0)*64 + (((kb*32 + (l&15)*2) ^ (((prw0+0)&7)<<4))>>1)] = (u16)u01;
      Pl[w][(prw0+1)*64 + (((kb*32 + (l&15)*2) ^ (((prw0+1)&7)<<4))>>1)] = (u16)(u01>>16);
      Pl[w][(prw0+2)*64 + (((kb*32 + (l&15)*2) ^ (((prw0+2)&7)<<4))>>1)] = (u16)u23;
      Pl[w][(prw0+3)*64 + (((kb*32 + (l&15)*2) ^ (((prw0+3)&7)<<4))>>1)] = (u16)(u23>>16);
    }
    short8 pa[2];
    #pragma unroll
    for (int s=0;s<2;s++)
      pa[s] = *(const short8*)&Pl[w][(l&15)*64 + (((s*64 + (l>>4)*16) ^ (((l&15)&7)<<4))>>1)];
    // ---- PV
    #pragma unroll
    for (int d=0;d<4;d++){
      const int vrow = d*16 + (l&15);
      #pragma unroll
      for (int s=0;s<2;s++){
        int boff = vrow*128 + ((s*64 + (l>>4)*16) ^ ((vrow&7)<<4));
        short8 vf = *(const short8*)((const char*)&Vl[0] + boff);
        ao[d] = __builtin_amdgcn_mfma_f32_16x16x32_bf16(pa[s], vf, ao[d], 0,0,0);
      }
    }
    if (tn < 0) break;
    // ---- single-buffer handoff: wait all reads, overwrite, wait writes
    __syncthreads();
    #pragma unroll
    for (int it=0;it<2;++it){
      int slot=it*256+tid, row=slot>>3, c16=slot&7;
      int boff = row*128 + ((c16*16) ^ ((row&7)<<4));
      *(uint4*)((char*)&Kl[0] + boff) = kr[it];
      *(uint4*)((char*)&Vl[0] + boff) = vr[it];
    }
    __syncthreads();
    t = tn;
  }
  // ---- final row-sum reduce + coalesced epilogue through Pl
  #pragma unroll
  for (int r=0;r<4;r++){
    #pragma unroll
    for (int m=1;m<=8;m<<=1) lsum[r] += __shfl_xor(lsum[r], m, 64);
    lsum[r] = 1.0f / lsum[r];
  }
  #pragma unroll
  for (int d=0;d<4;d++){
    unsigned int u01 = cvt_pk_bf16(ao[d][0]*lsum[0], ao[d][1]*lsum[1]);
    unsigned int u23 = cvt_pk_bf16(ao[d][2]*lsum[2], ao[d][3]*lsum[3]);
    int prw0 = (l>>4)*4, col = d*16 + (l&15);
    Pl[w][(prw0+0)*64 + col] = (u16)u01;
    Pl[w][(prw0+1)*64 + col] = (u16)(u01>>16);
    Pl[w][(prw0+2)*64 + col] = (u16)u23;
    Pl[w][(prw0+3)*64 + col] = (u16)(u23>>16);
  }
  __builtin_amdgcn_s_waitcnt(0);  // wave-private Pl slice: order writes->reads
  {
    int r16 = l&15, cchunk = (l>>4)*16;
    uint4 v0 = *(const uint4*)&Pl[w][r16*64 + cchunk];
    uint4 v1 = *(const uint4*)&Pl[w][r16*64 + cchunk + 8];
    size_t orow = (size_t)(orow0 + q0 + w*16 + r16)*1536 + ocol + cchunk;
    *(uint4*)&Out[orow]     = v0;
    *(uint4*)&Out[orow + 8] = v1;
  }
}

extern "C" void kernel_launch(void* const* d_in, const int* in_sizes, int n_in,
                              void* d_out, int out_size, void* d_ws, size_t ws_size,
                              hipStream_t stream) {
  const float* x      = (const float*)d_in[0];
  const int*   patch  = (const int*)d_in[1];
  const float* sincos = (const float*)d_in[2];
  const float* ln1s   = (const float*)d_in[3];
  const float* wqkv   = (const float*)d_in[4];
  const float* aq     = (const float*)d_in[5];
  const float* ak     = (const float*)d_in[6];
  const float* aqs    = (const float*)d_in[7];
  const float* aks    = (const float*)d_in[8];
  const float* wout   = (const float*)d_in[9];
  const float* bout   = (const float*)d_in[10];
  const float* ls1    = (const float*)d_in[11];
  const float* ln2s   = (const float*)d_in[12];
  const float* ln2b   = (const float*)d_in[13];
  const float* wm1    = (const float*)d_in[14];
  const float* bm1    = (const float*)d_in[15];
  const float* wm2    = (const float*)d_in[16];
  const float* bm2    = (const float*)d_in[17];
  const float* ls2    = (const float*)d_in[18];
  float* out = (float*)d_out;

  char* ws = (char*)d_ws;
  size_t off = 0;
  auto alloc = [&](size_t bytes)->void*{ void* p = ws + off; off += (bytes + 255) & ~(size_t)255; return p; };
  u16*  wqkvT = (u16*)alloc(4608ull*768*2);
  u16*  woutT = (u16*)alloc(768ull*1536*2);
  u16*  wm1T  = (u16*)alloc(3072ull*768*2);
  u16*  wm2T  = (u16*)alloc(768ull*3072*2);
  u16*  xin   = (u16*)alloc(4096ull*768*2);
  u16*  qkvb  = (u16*)alloc(4096ull*4608*2);   // bf16 qkv; ALSO aliased by split-K partials P
  u16*  qg    = (u16*)alloc(3145728ull*2);     // (P spans qkvb+qg+kg = 50,331,648 B exactly)
  u16*  kg    = (u16*)alloc(3145728ull*2);
  u16*  vg    = (u16*)alloc(3145728ull*2);     // transposed [2][12][64][2048]
  u16*  qsg   = (u16*)alloc(3145728ull*2);
  u16*  ksg   = (u16*)alloc(3145728ull*2);
  u16*  vsg   = (u16*)alloc(3145728ull*2);     // transposed [8][12][64][512]
  u16*  cat   = (u16*)alloc(4096ull*1536*2);
  float* x0   = (float*)alloc(4096ull*768*4);
  u16*  x1    = (u16*)alloc(4096ull*768*2);
  u16*  hbuf  = (u16*)alloc(4096ull*3072*2);
  float* P    = (float*)qkvb;                  // 4 x 4096 x 768 f32 partial planes

  dim3 b256(256);
  wtrans_k<<<dim3(144,24),b256,0,stream>>>(wqkv, wqkvT, 768, 4608);
  wtrans_k<<<dim3(24,48),b256,0,stream>>>(wout, woutT, 1536, 768);
  wtrans_k<<<dim3(96,24),b256,0,stream>>>(wm1, wm1T, 768, 3072);
  wtrans_k<<<dim3(24,96),b256,0,stream>>>(wm2, wm2T, 3072, 768);
  ln1_k<<<4096,b256,0,stream>>>(x, ln1s, xin);
  gemm_k<3,1><<<dim3(36,32),b256,0,stream>>>(xin, wqkvT, 4096, 4608, 768, nullptr, qkvb, nullptr);
  postproc2_k<<<768,b256,0,stream>>>(qkvb, sincos, aq, ak, aqs, aks, qg,kg,vg,qsg,ksg,vsg);
  attn6_k<<<1536,b256,0,stream>>>(qg,kg,vg, qsg,ksg,vsg, cat, patch);
  gemm_k<0,4><<<dim3(6,32,4),b256,0,stream>>>(cat, woutT, 4096, 768, 1536, P, nullptr, nullptr);
  redln_k<<<4096,b256,0,stream>>>(P, bout, ls1, x, ln2s, ln2b, x0, x1);
  gemm_k<2,1><<<dim3(24,32),b256,0,stream>>>(x1, wm1T, 4096, 3072, 768, nullptr, hbuf, bm1);
  gemm_k<0,4><<<dim3(6,32,4),b256,0,stream>>>(hbuf, wm2T, 4096, 768, 3072, P, nullptr, nullptr);
  red_k<<<3072,b256,0,stream>>>(P, bm2, ls2, x0, out);
}

// Round 10
// 271.237 us; speedup vs baseline: 1.0233x; 1.0233x over previous
//
#include <hip/hip_runtime.h>

#define DEVI __device__ __forceinline__

typedef __attribute__((ext_vector_type(8))) short short8;
typedef __attribute__((ext_vector_type(4))) float f32x4;
typedef unsigned short u16;

DEVI u16 f2bf(float f){
  unsigned int u = __float_as_uint(f);
  unsigned int r = (u + 0x7FFFu + ((u>>16)&1u)) >> 16;
  return (u16)r;
}
DEVI float bf2f(u16 h){ return __uint_as_float(((unsigned int)h)<<16); }

DEVI unsigned int cvt_pk_bf16(float a, float b){
  unsigned int r;
  asm("v_cvt_pk_bf16_f32 %0, %1, %2" : "=v"(r) : "v"(a), "v"(b));
  return r;   // lo = bf16(a), hi = bf16(b)
}

DEVI float gelu_f(float x){
  float x3 = x*x*x;
  float t = tanhf(0.7978845608028654f*(x + 0.044715f*x3));
  return 0.5f*x*(1.0f + t);
}

DEVI void async_cp16(const void* g, void* l){
  __builtin_amdgcn_global_load_lds(
      (const __attribute__((address_space(1))) unsigned int*)g,
      (__attribute__((address_space(3))) unsigned int*)l, 16, 0, 0);
}

// ---------------- weight transpose + bf16 convert: w (K x N) f32 -> wt (N x K) bf16
__global__ __launch_bounds__(256) void wtrans_k(const float* __restrict__ w,
                                                u16* __restrict__ wt, int K, int N){
  __shared__ float tile[32][33];
  int tn = blockIdx.x*32, tk = blockIdx.y*32;
  int r = threadIdx.x>>3, c4 = (threadIdx.x&7)*4;
  float4 vv = *(const float4*)&w[(size_t)(tk+r)*N + tn + c4];
  tile[r][c4+0]=vv.x; tile[r][c4+1]=vv.y; tile[r][c4+2]=vv.z; tile[r][c4+3]=vv.w;
  __syncthreads();
  u16 o[4];
  #pragma unroll
  for (int j=0;j<4;j++) o[j] = f2bf(tile[c4+j][r]);
  unsigned long long pk = (unsigned long long)o[0] | ((unsigned long long)o[1]<<16)
                        | ((unsigned long long)o[2]<<32) | ((unsigned long long)o[3]<<48);
  *(unsigned long long*)&wt[(size_t)(tn+r)*K + tk + c4] = pk;
}

// ---------------- LN1: x f32 (4096x768) -> xin bf16
__global__ __launch_bounds__(256) void ln1_k(const float* __restrict__ x,
                                             const float* __restrict__ sc,
                                             u16* __restrict__ xin){
  int row = blockIdx.x, tid = threadIdx.x;
  const float* xr = x + (size_t)row*768;
  float v[3]; float s=0.f, ss=0.f;
  #pragma unroll
  for (int i=0;i<3;i++){ v[i]=xr[tid+i*256]; s+=v[i]; ss+=v[i]*v[i]; }
  #pragma unroll
  for (int m=1;m<=32;m<<=1){ s += __shfl_xor(s,m,64); ss += __shfl_xor(ss,m,64); }
  __shared__ float ls0[4], ls1_[4];
  int w = tid>>6;
  if ((tid&63)==0){ ls0[w]=s; ls1_[w]=ss; }
  __syncthreads();
  s = ls0[0]+ls0[1]+ls0[2]+ls0[3]; ss = ls1_[0]+ls1_[1]+ls1_[2]+ls1_[3];
  float mu = s*(1.f/768.f);
  float var = ss*(1.f/768.f) - mu*mu;
  float inv = rsqrtf(var + 1e-6f);
  #pragma unroll
  for (int i=0;i<3;i++){ int c=tid+i*256; xin[(size_t)row*768+c] = f2bf((v[i]-mu)*inv*sc[c]); }
}

// ---------------- GEMM: C(MxN) = A(MxK,bf16) * Bt(NxK,bf16)^T
// EPI 0: f32 partial plane (split-K)   EPI 2: bf16(gelu(acc+bias))   EPI 3: plain bf16
template<int EPI, int SPLITK>
__global__ __launch_bounds__(256) void gemm_k(
    const u16* __restrict__ A, const u16* __restrict__ Bt,
    int M, int N, int K,
    float* __restrict__ Cf, u16* __restrict__ Cb,
    const float* __restrict__ bias)
{
  __shared__ __align__(16) u16 Al[128*32];
  __shared__ __align__(16) u16 Bl[128*32];
  const int tid = threadIdx.x, w = tid>>6, l = tid&63;
  const int m0 = blockIdx.y*128, n0 = blockIdx.x*128;
  const int Ksub = K/SPLITK;
  const int kc = (SPLITK>1) ? blockIdx.z : 0;
  const int kbase = kc*Ksub;
  const int wr = (w>>1)*64, wc = (w&1)*64;
  f32x4 acc[4][4];
  #pragma unroll
  for (int i=0;i<4;i++)
    #pragma unroll
    for (int j=0;j<4;j++){ f32x4 z={0.f,0.f,0.f,0.f}; acc[i][j]=z; }
  const int lr = l>>2, lc = l&3;
  for (int k0=0; k0<Ksub; k0+=32){
    __syncthreads();
    #pragma unroll
    for (int it=0; it<2; ++it){
      int arow = w*32 + it*16;
      async_cp16(A  + (size_t)(m0+arow+lr)*K + kbase + k0 + lc*8, &Al[arow*32]);
      async_cp16(Bt + (size_t)(n0+arow+lr)*K + kbase + k0 + lc*8, &Bl[arow*32]);
    }
    __syncthreads();
    short8 af[4], bfr[4];
    #pragma unroll
    for (int mi=0;mi<4;++mi) af[mi]  = *(const short8*)&Al[(wr+mi*16+(l&15))*32 + (l>>4)*8];
    #pragma unroll
    for (int ni=0;ni<4;++ni) bfr[ni] = *(const short8*)&Bl[(wc+ni*16+(l&15))*32 + (l>>4)*8];
    #pragma unroll
    for (int mi=0;mi<4;++mi)
      #pragma unroll
      for (int ni=0;ni<4;++ni)
        acc[mi][ni] = __builtin_amdgcn_mfma_f32_16x16x32_bf16(af[mi], bfr[ni], acc[mi][ni], 0,0,0);
  }
  #pragma unroll
  for (int mi=0;mi<4;++mi){
    int rb = m0 + wr + mi*16 + ((l>>4)<<2);
    #pragma unroll
    for (int ni=0;ni<4;++ni){
      int col = n0 + wc + ni*16 + (l&15);
      #pragma unroll
      for (int r=0;r<4;r++){
        int row = rb + r;
        float v = acc[mi][ni][r];
        if (EPI==0)      Cf[((size_t)kc*M + row)*N + col] = v;
        else if (EPI==2) Cb[(size_t)row*N+col] = f2bf(gelu_f(v + bias[col]));
        else             Cb[(size_t)row*N+col] = f2bf(v);
      }
    }
  }
}

// ---------------- split-K reduce + bias/ls/resid + LN2 + gelu (out-proj path)
__global__ __launch_bounds__(256) void redln_k(
    const float* __restrict__ P, const float* __restrict__ bias,
    const float* __restrict__ lsc, const float* __restrict__ resid,
    const float* __restrict__ ln2sc, const float* __restrict__ ln2bi,
    float* __restrict__ x0, u16* __restrict__ x1)
{
  const size_t MN = 4096ull*768;
  int row = blockIdx.x, tid = threadIdx.x;
  float v[3]; float s=0.f, ss=0.f;
  #pragma unroll
  for (int i=0;i<3;i++){
    int c = tid + i*256;
    size_t idx = (size_t)row*768 + c;
    float acc = P[idx] + P[MN+idx] + P[2*MN+idx] + P[3*MN+idx];
    float y = lsc[c]*(acc + bias[c]) + resid[idx];
    x0[idx] = y;
    v[i] = y; s += y; ss += y*y;
  }
  #pragma unroll
  for (int m=1;m<=32;m<<=1){ s += __shfl_xor(s,m,64); ss += __shfl_xor(ss,m,64); }
  __shared__ float ls0[4], ls1_[4];
  int w = tid>>6;
  if ((tid&63)==0){ ls0[w]=s; ls1_[w]=ss; }
  __syncthreads();
  s = ls0[0]+ls0[1]+ls0[2]+ls0[3]; ss = ls1_[0]+ls1_[1]+ls1_[2]+ls1_[3];
  float mu = s*(1.f/768.f);
  float var = ss*(1.f/768.f) - mu*mu;
  float inv = rsqrtf(var + 1e-6f);
  #pragma unroll
  for (int i=0;i<3;i++){
    int c = tid + i*256;
    float y = (v[i]-mu)*inv*ln2sc[c] + ln2bi[c];
    x1[(size_t)row*768 + c] = f2bf(gelu_f(y));
  }
}

// ---------------- split-K reduce + bias/ls/resid (final output)
__global__ __launch_bounds__(256) void red_k(
    const float* __restrict__ P, const float* __restrict__ bias,
    const float* __restrict__ lsc, const float* __restrict__ resid,
    float* __restrict__ out)
{
  const size_t MN = 4096ull*768;
  size_t i = ((size_t)blockIdx.x*256 + threadIdx.x)*4;
  int c = (int)(i % 768);
  float4 a0 = *(const float4*)&P[i];
  float4 a1 = *(const float4*)&P[MN+i];
  float4 a2 = *(const float4*)&P[2*MN+i];
  float4 a3 = *(const float4*)&P[3*MN+i];
  float4 bi = *(const float4*)&bias[c];
  float4 ls = *(const float4*)&lsc[c];
  float4 rs = *(const float4*)&resid[i];
  float4 o;
  o.x = ls.x*(a0.x+a1.x+a2.x+a3.x + bi.x) + rs.x;
  o.y = ls.y*(a0.y+a1.y+a2.y+a3.y + bi.y) + rs.y;
  o.z = ls.z*(a0.z+a1.z+a2.z+a3.z + bi.z) + rs.z;
  o.w = ls.w*(a0.w+a1.w+a2.w+a3.w + bi.w) + rs.w;
  *(float4*)&out[i] = o;
}

// ---------------- qkv postprocess v2: tile kernel, rms+rope in-register,
// V transposed through padded LDS so ALL global writes are coalesced.
__global__ __launch_bounds__(256) void postproc2_k(
  const u16* __restrict__ qkv, const float* __restrict__ sincos,
  const float* __restrict__ aq, const float* __restrict__ ak,
  const float* __restrict__ aqs, const float* __restrict__ aks,
  u16* __restrict__ qg, u16* __restrict__ kg, u16* __restrict__ vg,
  u16* __restrict__ qsg, u16* __restrict__ ksg, u16* __restrict__ vsg)
{
  __shared__ u16 vt[2][64*66];   // [t][d] padded: row stride 66 u16 (132 B)
  const int bid = blockIdx.x;
  const int b = bid/384; int r0 = bid - b*384;
  const int v = r0/96;   int r1 = r0 - v*96;
  const int t6 = r1/12;  const int h = r1 - t6*12;
  const int T0 = t6*64;
  const int tid = threadIdx.x, w = tid>>6, l = tid&63;
  const int tq = l>>4, dq = l&15;
  const int m0 = b*2048 + v*512;
  const size_t gQbase = ((size_t)(b*12) + h)*2048 + v*512;
  const size_t sQbase = ((size_t)((v*2+b)*12) + h)*512;

  // ---- q / k / qs / ks: rms + rope, row-coalesced writes
  #pragma unroll
  for (int qi=0; qi<4; ++qi){
    const int tt = (qi<2) ? qi : qi+1;          // 0,1,3,4
    const float* al = (qi==0)?aq:(qi==1)?ak:(qi==2)?aqs:aks;
    float4 alv = *(const float4*)&al[h*64 + dq*4];
    u16* dst = (qi==0)?qg:(qi==1)?kg:(qi==2)?qsg:ksg;
    const size_t obase = (qi<2) ? gQbase : sQbase;
    #pragma unroll
    for (int it=0; it<4; ++it){
      const int t = T0 + w*16 + it*4 + tq;
      const u16* src = &qkv[(size_t)(m0+t)*4608 + tt*768 + h*64 + dq*4];
      ushort2 u01 = *(const ushort2*)src;
      ushort2 u23 = *(const ushort2*)(src+2);
      float x0=bf2f(u01.x), x1=bf2f(u01.y), x2=bf2f(u23.x), x3=bf2f(u23.y);
      float ss = x0*x0+x1*x1+x2*x2+x3*x3;
      #pragma unroll
      for (int mm=1;mm<=8;mm<<=1) ss += __shfl_xor(ss,mm,64);
      float rinv = rsqrtf(ss*(1.f/64.f) + 1e-5f);
      x0 *= alv.x*rinv; x1 *= alv.y*rinv; x2 *= alv.z*rinv; x3 *= alv.w*rinv;
      float4 cs01 = *(const float4*)&sincos[(size_t)(t*64 + dq*4)*2];
      float4 cs23 = *(const float4*)&sincos[(size_t)(t*64 + dq*4)*2 + 4];
      float y0 = x0*cs01.x - x1*cs01.y;
      float y1 = x1*cs01.z + x0*cs01.w;
      float y2 = x2*cs23.x - x3*cs23.y;
      float y3 = x3*cs23.z + x2*cs23.w;
      unsigned int lo = cvt_pk_bf16(y0, y1);
      unsigned int hi = cvt_pk_bf16(y2, y3);
      unsigned int* po = (unsigned int*)&dst[(obase + t)*64 + dq*4];
      po[0] = lo; po[1] = hi;
    }
  }

  // ---- v / vs: stage [t][d] tiles in LDS, write transposed [d][t] coalesced
  #pragma unroll
  for (int vi=0; vi<2; ++vi){
    const int tt = (vi==0) ? 2 : 5;
    #pragma unroll
    for (int it=0; it<4; ++it){
      const int t = T0 + w*16 + it*4 + tq;
      const int tl = w*16 + it*4 + tq;
      const u16* src = &qkv[(size_t)(m0+t)*4608 + tt*768 + h*64 + dq*4];
      ushort2 u01 = *(const ushort2*)src;
      ushort2 u23 = *(const ushort2*)(src+2);
      unsigned int* pl = (unsigned int*)&vt[vi][tl*66 + dq*4];
      pl[0] = (unsigned int)u01.x | ((unsigned int)u01.y<<16);
      pl[1] = (unsigned int)u23.x | ((unsigned int)u23.y<<16);
    }
  }
  __syncthreads();
  {
    const size_t vgb = (((size_t)(b*12) + h)*64)*2048 + v*512 + T0 + l;
    #pragma unroll
    for (int i=0;i<16;++i){
      int d = w*16 + i;
      vg[vgb + (size_t)d*2048] = vt[0][l*66 + d];
    }
    const size_t vsb = (((size_t)((v*2+b)*12) + h)*64)*512 + T0 + l;
    #pragma unroll
    for (int i=0;i<16;++i){
      int d = w*16 + i;
      vsg[vsb + (size_t)d*512] = vt[1][l*66 + d];
    }
  }
}

// ---------------- merged segment-masked flash attention, QBLK=64, 1536 blocks
// Q/K: [seq][h][L][64] bf16 ; Vt: [seq][h][64][L] bf16 ; Out bf16 [4096][1536]
// Direct exp (|s|<=8, rms-norm'd q/k). Single-buffered K/V LDS (~25KB).
// amdgpu_waves_per_eu(4,4): pin occupancy at 4 waves/EU so the compiler gets
// the FULL 128-VGPR budget (launch_bounds(256,4) alone let the heuristic
// target 8 waves/EU -> 56 VGPR -> 100MB/dispatch scratch spill, R8/R9).
__global__ __launch_bounds__(256) __attribute__((amdgpu_waves_per_eu(4,4)))
void attn6_k(
  const u16* __restrict__ Qg, const u16* __restrict__ Kg, const u16* __restrict__ Vtg,
  const u16* __restrict__ Qs, const u16* __restrict__ Ks, const u16* __restrict__ Vts,
  u16* __restrict__ Out, const int* __restrict__ pids)
{
  __shared__ __align__(16) u16 Kl[64*64];
  __shared__ __align__(16) u16 Vl[64*64];
  __shared__ __align__(16) u16 Pl[4][16*64];
  __shared__ unsigned long long amask_s;
  const int gid = blockIdx.x;
  // balanced XCD swizzle: each XCD gets 96 global + 96 shifted contiguous blocks
  const int xcd = gid & 7, idx = gid >> 3;
  const int lid = (idx < 96) ? xcd*96 + idx : 768 + xcd*96 + (idx - 96);
  const int tid = threadIdx.x, w = tid>>6, l = tid&63;
  const u16 *Q, *K, *Vt; const int* prow;
  int L, seq, h, qb, orow0, ocol;
  if (lid < 768){
    seq = lid/384; int rem2 = lid - seq*384; h = rem2>>5; qb = rem2&31;
    Q=Qg; K=Kg; Vt=Vtg; L=2048;
    prow = pids + seq*512; orow0 = seq*2048; ocol = h*64;
  } else {
    int g2 = lid - 768; seq = g2/96; int rem2 = g2 - seq*96; h = rem2>>3; qb = rem2&7;
    Q=Qs; K=Ks; Vt=Vts; L=512;
    prow = pids + (seq&1)*512; orow0 = (seq&1)*2048 + (seq>>1)*512; ocol = 768 + h*64;
  }
  const size_t base = ((size_t)(seq*12) + h)*(size_t)L*64;
  const int q0 = qb*64, tq0 = q0 & 511;
  short8 qf[2];
  const int qrow = q0 + w*16 + (l&15);
  #pragma unroll
  for (int s=0;s<2;s++) qf[s] = *(const short8*)&Q[base + (size_t)qrow*64 + s*32 + (l>>4)*8];
  const int qlo = prow[tq0], qhi = prow[tq0+63];
  int sq[4];
  #pragma unroll
  for (int r=0;r<4;r++) sq[r] = prow[tq0 + w*16 + (l>>4)*4 + r];
  float lsum[4]; f32x4 ao[4];
  #pragma unroll
  for (int r=0;r<4;r++) lsum[r]=0.f;
  #pragma unroll
  for (int d=0;d<4;d++){ f32x4 z={0.f,0.f,0.f,0.f}; ao[d]=z; }
  const int nk = L/64;
  // ---- active-tile bitmask (uniform): wave 0 ballots over segment ranges
  bool act = false;
  if (tid < 64 && tid < nk){
    int tk0 = (tid*64)&511;
    act = (prow[tk0+63] >= qlo) && (prow[tk0] <= qhi);
  }
  unsigned long long bm = __ballot(act);
  if (tid==0) amask_s = bm;
  __syncthreads();
  unsigned long long rem = amask_s;   // non-empty: diagonal tile always active
  int t = (int)(__ffsll((unsigned long long)rem)-1); rem &= rem-1;
  uint4 kr[2], vr[2];
  {  // prologue: stage first tile
    int k0 = t*64;
    #pragma unroll
    for (int it=0;it<2;++it){
      int slot=it*256+tid, row=slot>>3, c16=slot&7;
      kr[it] = *(const uint4*)&K[base + (size_t)(k0+row)*64 + c16*8];
      vr[it] = *(const uint4*)&Vt[base + (size_t)row*(size_t)L + k0 + c16*8];
    }
    #pragma unroll
    for (int it=0;it<2;++it){
      int slot=it*256+tid, row=slot>>3, c16=slot&7;
      int boff = row*128 + ((c16*16) ^ ((row&7)<<4));
      *(uint4*)((char*)&Kl[0] + boff) = kr[it];
      *(uint4*)((char*)&Vl[0] + boff) = vr[it];
    }
  }
  __syncthreads();
  while (true){
    int tn = rem ? (int)(__ffsll((unsigned long long)rem)-1) : -1;
    if (tn >= 0){           // issue next tile's loads now; they land during compute
      rem &= rem-1;
      int k0n = tn*64;
      #pragma unroll
      for (int it=0;it<2;++it){
        int slot=it*256+tid, row=slot>>3, c16=slot&7;
        kr[it] = *(const uint4*)&K[base + (size_t)(k0n+row)*64 + c16*8];
        vr[it] = *(const uint4*)&Vt[base + (size_t)row*(size_t)L + k0n + c16*8];
      }
    }
    // ---- compute current tile from LDS
    const int tk0 = (t*64) & 511;
    int skv[4];
    #pragma unroll
    for (int kb=0;kb<4;kb++) skv[kb] = prow[tk0 + kb*16 + (l&15)];
    // ---- QK^T
    f32x4 s4[4];
    #pragma unroll
    for (int kb=0;kb<4;kb++){
      const int krow = kb*16 + (l&15);
      f32x4 a = {0.f,0.f,0.f,0.f};
      #pragma unroll
      for (int s=0;s<2;s++){
        int boff = krow*128 + ((s*64 + (l>>4)*16) ^ ((krow&7)<<4));
        short8 kf = *(const short8*)((const char*)&Kl[0] + boff);
        a = __builtin_amdgcn_mfma_f32_16x16x32_bf16(qf[s], kf, a, 0,0,0);
      }
      s4[kb] = a;
    }
    // ---- mask + direct exp + P relayout (cvt_pk pairs)
    #pragma unroll
    for (int kb=0;kb<4;kb++){
      float p0 = (skv[kb] == sq[0]) ? __expf(s4[kb][0]*0.125f) : 0.f;
      float p1 = (skv[kb] == sq[1]) ? __expf(s4[kb][1]*0.125f) : 0.f;
      float p2 = (skv[kb] == sq[2]) ? __expf(s4[kb][2]*0.125f) : 0.f;
      float p3 = (skv[kb] == sq[3]) ? __expf(s4[kb][3]*0.125f) : 0.f;
      lsum[0]+=p0; lsum[1]+=p1; lsum[2]+=p2; lsum[3]+=p3;
      unsigned int u01 = cvt_pk_bf16(p0, p1);
      unsigned int u23 = cvt_pk_bf16(p2, p3);
      int prw0 = (l>>4)*4;
      Pl[w][(prw0+0)*64 + (((kb*32 + (l&15)*2) ^ (((prw0+0)&7)<<4))>>1)] = (u16)u01;
      Pl[w][(prw0+1)*64 + (((kb*32 + (l&15)*2) ^ (((prw0+1)&7)<<4))>>1)] = (u16)(u01>>16);
      Pl[w][(prw0+2)*64 + (((kb*32 + (l&15)*2) ^ (((prw0+2)&7)<<4))>>1)] = (u16)u23;
      Pl[w][(prw0+3)*64 + (((kb*32 + (l&15)*2) ^ (((prw0+3)&7)<<4))>>1)] = (u16)(u23>>16);
    }
    short8 pa[2];
    #pragma unroll
    for (int s=0;s<2;s++)
      pa[s] = *(const short8*)&Pl[w][(l&15)*64 + (((s*64 + (l>>4)*16) ^ (((l&15)&7)<<4))>>1)];
    // ---- PV
    #pragma unroll
    for (int d=0;d<4;d++){
      const int vrow = d*16 + (l&15);
      #pragma unroll
      for (int s=0;s<2;s++){
        int boff = vrow*128 + ((s*64 + (l>>4)*16) ^ ((vrow&7)<<4));
        short8 vf = *(const short8*)((const char*)&Vl[0] + boff);
        ao[d] = __builtin_amdgcn_mfma_f32_16x16x32_bf16(pa[s], vf, ao[d], 0,0,0);
      }
    }
    if (tn < 0) break;
    // ---- single-buffer handoff: wait all reads, overwrite, wait writes
    __syncthreads();
    #pragma unroll
    for (int it=0;it<2;++it){
      int slot=it*256+tid, row=slot>>3, c16=slot&7;
      int boff = row*128 + ((c16*16) ^ ((row&7)<<4));
      *(uint4*)((char*)&Kl[0] + boff) = kr[it];
      *(uint4*)((char*)&Vl[0] + boff) = vr[it];
    }
    __syncthreads();
    t = tn;
  }
  // ---- final row-sum reduce + coalesced epilogue through Pl
  #pragma unroll
  for (int r=0;r<4;r++){
    #pragma unroll
    for (int m=1;m<=8;m<<=1) lsum[r] += __shfl_xor(lsum[r], m, 64);
    lsum[r] = 1.0f / lsum[r];
  }
  #pragma unroll
  for (int d=0;d<4;d++){
    unsigned int u01 = cvt_pk_bf16(ao[d][0]*lsum[0], ao[d][1]*lsum[1]);
    unsigned int u23 = cvt_pk_bf16(ao[d][2]*lsum[2], ao[d][3]*lsum[3]);
    int prw0 = (l>>4)*4, col = d*16 + (l&15);
    Pl[w][(prw0+0)*64 + col] = (u16)u01;
    Pl[w][(prw0+1)*64 + col] = (u16)(u01>>16);
    Pl[w][(prw0+2)*64 + col] = (u16)u23;
    Pl[w][(prw0+3)*64 + col] = (u16)(u23>>16);
  }
  __builtin_amdgcn_s_waitcnt(0);  // wave-private Pl slice: order writes->reads
  {
    int r16 = l&15, cchunk = (l>>4)*16;
    uint4 v0 = *(const uint4*)&Pl[w][r16*64 + cchunk];
    uint4 v1 = *(const uint4*)&Pl[w][r16*64 + cchunk + 8];
    size_t orow = (size_t)(orow0 + q0 + w*16 + r16)*1536 + ocol + cchunk;
    *(uint4*)&Out[orow]     = v0;
    *(uint4*)&Out[orow + 8] = v1;
  }
}

extern "C" void kernel_launch(void* const* d_in, const int* in_sizes, int n_in,
                              void* d_out, int out_size, void* d_ws, size_t ws_size,
                              hipStream_t stream) {
  const float* x      = (const float*)d_in[0];
  const int*   patch  = (const int*)d_in[1];
  const float* sincos = (const float*)d_in[2];
  const float* ln1s   = (const float*)d_in[3];
  const float* wqkv   = (const float*)d_in[4];
  const float* aq     = (const float*)d_in[5];
  const float* ak     = (const float*)d_in[6];
  const float* aqs    = (const float*)d_in[7];
  const float* aks    = (const float*)d_in[8];
  const float* wout   = (const float*)d_in[9];
  const float* bout   = (const float*)d_in[10];
  const float* ls1    = (const float*)d_in[11];
  const float* ln2s   = (const float*)d_in[12];
  const float* ln2b   = (const float*)d_in[13];
  const float* wm1    = (const float*)d_in[14];
  const float* bm1    = (const float*)d_in[15];
  const float* wm2    = (const float*)d_in[16];
  const float* bm2    = (const float*)d_in[17];
  const float* ls2    = (const float*)d_in[18];
  float* out = (float*)d_out;

  char* ws = (char*)d_ws;
  size_t off = 0;
  auto alloc = [&](size_t bytes)->void*{ void* p = ws + off; off += (bytes + 255) & ~(size_t)255; return p; };
  u16*  wqkvT = (u16*)alloc(4608ull*768*2);
  u16*  woutT = (u16*)alloc(768ull*1536*2);
  u16*  wm1T  = (u16*)alloc(3072ull*768*2);
  u16*  wm2T  = (u16*)alloc(768ull*3072*2);
  u16*  xin   = (u16*)alloc(4096ull*768*2);
  u16*  qkvb  = (u16*)alloc(4096ull*4608*2);   // bf16 qkv; ALSO aliased by split-K partials P
  u16*  qg    = (u16*)alloc(3145728ull*2);     // (P spans qkvb+qg+kg = 50,331,648 B exactly)
  u16*  kg    = (u16*)alloc(3145728ull*2);
  u16*  vg    = (u16*)alloc(3145728ull*2);     // transposed [2][12][64][2048]
  u16*  qsg   = (u16*)alloc(3145728ull*2);
  u16*  ksg   = (u16*)alloc(3145728ull*2);
  u16*  vsg   = (u16*)alloc(3145728ull*2);     // transposed [8][12][64][512]
  u16*  cat   = (u16*)alloc(4096ull*1536*2);
  float* x0   = (float*)alloc(4096ull*768*4);
  u16*  x1    = (u16*)alloc(4096ull*768*2);
  u16*  hbuf  = (u16*)alloc(4096ull*3072*2);
  float* P    = (float*)qkvb;                  // 4 x 4096 x 768 f32 partial planes

  dim3 b256(256);
  wtrans_k<<<dim3(144,24),b256,0,stream>>>(wqkv, wqkvT, 768, 4608);
  wtrans_k<<<dim3(24,48),b256,0,stream>>>(wout, woutT, 1536, 768);
  wtrans_k<<<dim3(96,24),b256,0,stream>>>(wm1, wm1T, 768, 3072);
  wtrans_k<<<dim3(24,96),b256,0,stream>>>(wm2, wm2T, 3072, 768);
  ln1_k<<<4096,b256,0,stream>>>(x, ln1s, xin);
  gemm_k<3,1><<<dim3(36,32),b256,0,stream>>>(xin, wqkvT, 4096, 4608, 768, nullptr, qkvb, nullptr);
  postproc2_k<<<768,b256,0,stream>>>(qkvb, sincos, aq, ak, aqs, aks, qg,kg,vg,qsg,ksg,vsg);
  attn6_k<<<1536,b256,0,stream>>>(qg,kg,vg, qsg,ksg,vsg, cat, patch);
  gemm_k<0,4><<<dim3(6,32,4),b256,0,stream>>>(cat, woutT, 4096, 768, 1536, P, nullptr, nullptr);
  redln_k<<<4096,b256,0,stream>>>(P, bout, ls1, x, ln2s, ln2b, x0, x1);
  gemm_k<2,1><<<dim3(24,32),b256,0,stream>>>(x1, wm1T, 4096, 3072, 768, nullptr, hbuf, bm1);
  gemm_k<0,4><<<dim3(6,32,4),b256,0,stream>>>(hbuf, wm2T, 4096, 768, 3072, P, nullptr, nullptr);
  red_k<<<3072,b256,0,stream>>>(P, bm2, ls2, x0, out);
}

// Round 11
// 248.947 us; speedup vs baseline: 1.1150x; 1.0895x over previous
//
#include <hip/hip_runtime.h>

#define DEVI __device__ __forceinline__

typedef __attribute__((ext_vector_type(8))) short short8;
typedef __attribute__((ext_vector_type(4))) float f32x4;
typedef unsigned short u16;

DEVI u16 f2bf(float f){
  unsigned int u = __float_as_uint(f);
  unsigned int r = (u + 0x7FFFu + ((u>>16)&1u)) >> 16;
  return (u16)r;
}
DEVI float bf2f(u16 h){ return __uint_as_float(((unsigned int)h)<<16); }

DEVI unsigned int cvt_pk_bf16(float a, float b){
  unsigned int r;
  asm("v_cvt_pk_bf16_f32 %0, %1, %2" : "=v"(r) : "v"(a), "v"(b));
  return r;   // lo = bf16(a), hi = bf16(b)
}

DEVI float gelu_f(float x){
  float x3 = x*x*x;
  float t = tanhf(0.7978845608028654f*(x + 0.044715f*x3));
  return 0.5f*x*(1.0f + t);
}

DEVI void async_cp16(const void* g, void* l){
  __builtin_amdgcn_global_load_lds(
      (const __attribute__((address_space(1))) unsigned int*)g,
      (__attribute__((address_space(3))) unsigned int*)l, 16, 0, 0);
}

// ---------------- weight transpose + bf16 convert: w (K x N) f32 -> wt (N x K) bf16
__global__ __launch_bounds__(256) void wtrans_k(const float* __restrict__ w,
                                                u16* __restrict__ wt, int K, int N){
  __shared__ float tile[32][33];
  int tn = blockIdx.x*32, tk = blockIdx.y*32;
  int r = threadIdx.x>>3, c4 = (threadIdx.x&7)*4;
  float4 vv = *(const float4*)&w[(size_t)(tk+r)*N + tn + c4];
  tile[r][c4+0]=vv.x; tile[r][c4+1]=vv.y; tile[r][c4+2]=vv.z; tile[r][c4+3]=vv.w;
  __syncthreads();
  u16 o[4];
  #pragma unroll
  for (int j=0;j<4;j++) o[j] = f2bf(tile[c4+j][r]);
  unsigned long long pk = (unsigned long long)o[0] | ((unsigned long long)o[1]<<16)
                        | ((unsigned long long)o[2]<<32) | ((unsigned long long)o[3]<<48);
  *(unsigned long long*)&wt[(size_t)(tn+r)*K + tk + c4] = pk;
}

// ---------------- LN1: x f32 (4096x768) -> xin bf16
__global__ __launch_bounds__(256) void ln1_k(const float* __restrict__ x,
                                             const float* __restrict__ sc,
                                             u16* __restrict__ xin){
  int row = blockIdx.x, tid = threadIdx.x;
  const float* xr = x + (size_t)row*768;
  float v[3]; float s=0.f, ss=0.f;
  #pragma unroll
  for (int i=0;i<3;i++){ v[i]=xr[tid+i*256]; s+=v[i]; ss+=v[i]*v[i]; }
  #pragma unroll
  for (int m=1;m<=32;m<<=1){ s += __shfl_xor(s,m,64); ss += __shfl_xor(ss,m,64); }
  __shared__ float ls0[4], ls1_[4];
  int w = tid>>6;
  if ((tid&63)==0){ ls0[w]=s; ls1_[w]=ss; }
  __syncthreads();
  s = ls0[0]+ls0[1]+ls0[2]+ls0[3]; ss = ls1_[0]+ls1_[1]+ls1_[2]+ls1_[3];
  float mu = s*(1.f/768.f);
  float var = ss*(1.f/768.f) - mu*mu;
  float inv = rsqrtf(var + 1e-6f);
  #pragma unroll
  for (int i=0;i<3;i++){ int c=tid+i*256; xin[(size_t)row*768+c] = f2bf((v[i]-mu)*inv*sc[c]); }
}

// ---------------- GEMM: C(MxN) = A(MxK,bf16) * Bt(NxK,bf16)^T
// EPI 0: f32 partial plane (split-K)   EPI 2: bf16(gelu(acc+bias))   EPI 3: plain bf16
template<int EPI, int SPLITK>
__global__ __launch_bounds__(256) void gemm_k(
    const u16* __restrict__ A, const u16* __restrict__ Bt,
    int M, int N, int K,
    float* __restrict__ Cf, u16* __restrict__ Cb,
    const float* __restrict__ bias)
{
  __shared__ __align__(16) u16 Al[128*32];
  __shared__ __align__(16) u16 Bl[128*32];
  const int tid = threadIdx.x, w = tid>>6, l = tid&63;
  const int m0 = blockIdx.y*128, n0 = blockIdx.x*128;
  const int Ksub = K/SPLITK;
  const int kc = (SPLITK>1) ? blockIdx.z : 0;
  const int kbase = kc*Ksub;
  const int wr = (w>>1)*64, wc = (w&1)*64;
  f32x4 acc[4][4];
  #pragma unroll
  for (int i=0;i<4;i++)
    #pragma unroll
    for (int j=0;j<4;j++){ f32x4 z={0.f,0.f,0.f,0.f}; acc[i][j]=z; }
  const int lr = l>>2, lc = l&3;
  for (int k0=0; k0<Ksub; k0+=32){
    __syncthreads();
    #pragma unroll
    for (int it=0; it<2; ++it){
      int arow = w*32 + it*16;
      async_cp16(A  + (size_t)(m0+arow+lr)*K + kbase + k0 + lc*8, &Al[arow*32]);
      async_cp16(Bt + (size_t)(n0+arow+lr)*K + kbase + k0 + lc*8, &Bl[arow*32]);
    }
    __syncthreads();
    short8 af[4], bfr[4];
    #pragma unroll
    for (int mi=0;mi<4;++mi) af[mi]  = *(const short8*)&Al[(wr+mi*16+(l&15))*32 + (l>>4)*8];
    #pragma unroll
    for (int ni=0;ni<4;++ni) bfr[ni] = *(const short8*)&Bl[(wc+ni*16+(l&15))*32 + (l>>4)*8];
    #pragma unroll
    for (int mi=0;mi<4;++mi)
      #pragma unroll
      for (int ni=0;ni<4;++ni)
        acc[mi][ni] = __builtin_amdgcn_mfma_f32_16x16x32_bf16(af[mi], bfr[ni], acc[mi][ni], 0,0,0);
  }
  #pragma unroll
  for (int mi=0;mi<4;++mi){
    int rb = m0 + wr + mi*16 + ((l>>4)<<2);
    #pragma unroll
    for (int ni=0;ni<4;++ni){
      int col = n0 + wc + ni*16 + (l&15);
      #pragma unroll
      for (int r=0;r<4;r++){
        int row = rb + r;
        float v = acc[mi][ni][r];
        if (EPI==0)      Cf[((size_t)kc*M + row)*N + col] = v;
        else if (EPI==2) Cb[(size_t)row*N+col] = f2bf(gelu_f(v + bias[col]));
        else             Cb[(size_t)row*N+col] = f2bf(v);
      }
    }
  }
}

// ---------------- split-K reduce + bias/ls/resid + LN2 + gelu (out-proj path)
__global__ __launch_bounds__(256) void redln_k(
    const float* __restrict__ P, const float* __restrict__ bias,
    const float* __restrict__ lsc, const float* __restrict__ resid,
    const float* __restrict__ ln2sc, const float* __restrict__ ln2bi,
    float* __restrict__ x0, u16* __restrict__ x1)
{
  const size_t MN = 4096ull*768;
  int row = blockIdx.x, tid = threadIdx.x;
  float v[3]; float s=0.f, ss=0.f;
  #pragma unroll
  for (int i=0;i<3;i++){
    int c = tid + i*256;
    size_t idx = (size_t)row*768 + c;
    float acc = P[idx] + P[MN+idx] + P[2*MN+idx] + P[3*MN+idx];
    float y = lsc[c]*(acc + bias[c]) + resid[idx];
    x0[idx] = y;
    v[i] = y; s += y; ss += y*y;
  }
  #pragma unroll
  for (int m=1;m<=32;m<<=1){ s += __shfl_xor(s,m,64); ss += __shfl_xor(ss,m,64); }
  __shared__ float ls0[4], ls1_[4];
  int w = tid>>6;
  if ((tid&63)==0){ ls0[w]=s; ls1_[w]=ss; }
  __syncthreads();
  s = ls0[0]+ls0[1]+ls0[2]+ls0[3]; ss = ls1_[0]+ls1_[1]+ls1_[2]+ls1_[3];
  float mu = s*(1.f/768.f);
  float var = ss*(1.f/768.f) - mu*mu;
  float inv = rsqrtf(var + 1e-6f);
  #pragma unroll
  for (int i=0;i<3;i++){
    int c = tid + i*256;
    float y = (v[i]-mu)*inv*ln2sc[c] + ln2bi[c];
    x1[(size_t)row*768 + c] = f2bf(gelu_f(y));
  }
}

// ---------------- split-K reduce + bias/ls/resid (final output)
__global__ __launch_bounds__(256) void red_k(
    const float* __restrict__ P, const float* __restrict__ bias,
    const float* __restrict__ lsc, const float* __restrict__ resid,
    float* __restrict__ out)
{
  const size_t MN = 4096ull*768;
  size_t i = ((size_t)blockIdx.x*256 + threadIdx.x)*4;
  int c = (int)(i % 768);
  float4 a0 = *(const float4*)&P[i];
  float4 a1 = *(const float4*)&P[MN+i];
  float4 a2 = *(const float4*)&P[2*MN+i];
  float4 a3 = *(const float4*)&P[3*MN+i];
  float4 bi = *(const float4*)&bias[c];
  float4 ls = *(const float4*)&lsc[c];
  float4 rs = *(const float4*)&resid[i];
  float4 o;
  o.x = ls.x*(a0.x+a1.x+a2.x+a3.x + bi.x) + rs.x;
  o.y = ls.y*(a0.y+a1.y+a2.y+a3.y + bi.y) + rs.y;
  o.z = ls.z*(a0.z+a1.z+a2.z+a3.z + bi.z) + rs.z;
  o.w = ls.w*(a0.w+a1.w+a2.w+a3.w + bi.w) + rs.w;
  *(float4*)&out[i] = o;
}

// ---------------- qkv postprocess v2: tile kernel, rms+rope in-register,
// V transposed through padded LDS so ALL global writes are coalesced.
__global__ __launch_bounds__(256) void postproc2_k(
  const u16* __restrict__ qkv, const float* __restrict__ sincos,
  const float* __restrict__ aq, const float* __restrict__ ak,
  const float* __restrict__ aqs, const float* __restrict__ aks,
  u16* __restrict__ qg, u16* __restrict__ kg, u16* __restrict__ vg,
  u16* __restrict__ qsg, u16* __restrict__ ksg, u16* __restrict__ vsg)
{
  __shared__ u16 vt[2][64*66];   // [t][d] padded: row stride 66 u16 (132 B)
  const int bid = blockIdx.x;
  const int b = bid/384; int r0 = bid - b*384;
  const int v = r0/96;   int r1 = r0 - v*96;
  const int t6 = r1/12;  const int h = r1 - t6*12;
  const int T0 = t6*64;
  const int tid = threadIdx.x, w = tid>>6, l = tid&63;
  const int tq = l>>4, dq = l&15;
  const int m0 = b*2048 + v*512;
  const size_t gQbase = ((size_t)(b*12) + h)*2048 + v*512;
  const size_t sQbase = ((size_t)((v*2+b)*12) + h)*512;

  // ---- q / k / qs / ks: rms + rope, row-coalesced writes
  #pragma unroll
  for (int qi=0; qi<4; ++qi){
    const int tt = (qi<2) ? qi : qi+1;          // 0,1,3,4
    const float* al = (qi==0)?aq:(qi==1)?ak:(qi==2)?aqs:aks;
    float4 alv = *(const float4*)&al[h*64 + dq*4];
    u16* dst = (qi==0)?qg:(qi==1)?kg:(qi==2)?qsg:ksg;
    const size_t obase = (qi<2) ? gQbase : sQbase;
    #pragma unroll
    for (int it=0; it<4; ++it){
      const int t = T0 + w*16 + it*4 + tq;
      const u16* src = &qkv[(size_t)(m0+t)*4608 + tt*768 + h*64 + dq*4];
      ushort2 u01 = *(const ushort2*)src;
      ushort2 u23 = *(const ushort2*)(src+2);
      float x0=bf2f(u01.x), x1=bf2f(u01.y), x2=bf2f(u23.x), x3=bf2f(u23.y);
      float ss = x0*x0+x1*x1+x2*x2+x3*x3;
      #pragma unroll
      for (int mm=1;mm<=8;mm<<=1) ss += __shfl_xor(ss,mm,64);
      float rinv = rsqrtf(ss*(1.f/64.f) + 1e-5f);
      x0 *= alv.x*rinv; x1 *= alv.y*rinv; x2 *= alv.z*rinv; x3 *= alv.w*rinv;
      float4 cs01 = *(const float4*)&sincos[(size_t)(t*64 + dq*4)*2];
      float4 cs23 = *(const float4*)&sincos[(size_t)(t*64 + dq*4)*2 + 4];
      float y0 = x0*cs01.x - x1*cs01.y;
      float y1 = x1*cs01.z + x0*cs01.w;
      float y2 = x2*cs23.x - x3*cs23.y;
      float y3 = x3*cs23.z + x2*cs23.w;
      unsigned int lo = cvt_pk_bf16(y0, y1);
      unsigned int hi = cvt_pk_bf16(y2, y3);
      unsigned int* po = (unsigned int*)&dst[(obase + t)*64 + dq*4];
      po[0] = lo; po[1] = hi;
    }
  }

  // ---- v / vs: stage [t][d] tiles in LDS, write transposed [d][t] coalesced
  #pragma unroll
  for (int vi=0; vi<2; ++vi){
    const int tt = (vi==0) ? 2 : 5;
    #pragma unroll
    for (int it=0; it<4; ++it){
      const int t = T0 + w*16 + it*4 + tq;
      const int tl = w*16 + it*4 + tq;
      const u16* src = &qkv[(size_t)(m0+t)*4608 + tt*768 + h*64 + dq*4];
      ushort2 u01 = *(const ushort2*)src;
      ushort2 u23 = *(const ushort2*)(src+2);
      unsigned int* pl = (unsigned int*)&vt[vi][tl*66 + dq*4];
      pl[0] = (unsigned int)u01.x | ((unsigned int)u01.y<<16);
      pl[1] = (unsigned int)u23.x | ((unsigned int)u23.y<<16);
    }
  }
  __syncthreads();
  {
    const size_t vgb = (((size_t)(b*12) + h)*64)*2048 + v*512 + T0 + l;
    #pragma unroll
    for (int i=0;i<16;++i){
      int d = w*16 + i;
      vg[vgb + (size_t)d*2048] = vt[0][l*66 + d];
    }
    const size_t vsb = (((size_t)((v*2+b)*12) + h)*64)*512 + T0 + l;
    #pragma unroll
    for (int i=0;i<16;++i){
      int d = w*16 + i;
      vsg[vsb + (size_t)d*512] = vt[1][l*66 + d];
    }
  }
}

// ---------------- merged segment-masked flash attention, QBLK=64, 1536 blocks
// Q/K: [seq][h][L][64] bf16 ; Vt: [seq][h][64][L] bf16 ; Out bf16 [4096][1536]
// Direct exp (|s|<=8, rms-norm'd q/k). K/V staged via global_load_lds
// (NO VGPR round-trip: kills the kr/vr register pressure that caused R8-R10
// spills). LDS stays LINEAR; the XOR bank-swizzle is applied by pre-swizzling
// the GLOBAL source column (c16 ^ (row&7), involution) -> read side unchanged.
// Single buffer, 24KB LDS -> 6 blocks/CU; barrier drain covered by 24 waves/CU.
__global__ __launch_bounds__(256) void attn7_k(
  const u16* __restrict__ Qg, const u16* __restrict__ Kg, const u16* __restrict__ Vtg,
  const u16* __restrict__ Qs, const u16* __restrict__ Ks, const u16* __restrict__ Vts,
  u16* __restrict__ Out, const int* __restrict__ pids)
{
  __shared__ __align__(16) u16 Kl[64*64];
  __shared__ __align__(16) u16 Vl[64*64];
  __shared__ __align__(16) u16 Pl[4][16*64];
  __shared__ unsigned long long amask_s;
  const int gid = blockIdx.x;
  // balanced XCD swizzle: each XCD gets 96 global + 96 shifted contiguous blocks
  const int xcd = gid & 7, idx = gid >> 3;
  const int lid = (idx < 96) ? xcd*96 + idx : 768 + xcd*96 + (idx - 96);
  const int tid = threadIdx.x, w = tid>>6, l = tid&63;
  const u16 *Q, *K, *Vt; const int* prow;
  int L, seq, h, qb, orow0, ocol;
  if (lid < 768){
    seq = lid/384; int rem2 = lid - seq*384; h = rem2>>5; qb = rem2&31;
    Q=Qg; K=Kg; Vt=Vtg; L=2048;
    prow = pids + seq*512; orow0 = seq*2048; ocol = h*64;
  } else {
    int g2 = lid - 768; seq = g2/96; int rem2 = g2 - seq*96; h = rem2>>3; qb = rem2&7;
    Q=Qs; K=Ks; Vt=Vts; L=512;
    prow = pids + (seq&1)*512; orow0 = (seq&1)*2048 + (seq>>1)*512; ocol = 768 + h*64;
  }
  const size_t base = ((size_t)(seq*12) + h)*(size_t)L*64;
  const int q0 = qb*64, tq0 = q0 & 511;
  short8 qf[2];
  const int qrow = q0 + w*16 + (l&15);
  #pragma unroll
  for (int s=0;s<2;s++) qf[s] = *(const short8*)&Q[base + (size_t)qrow*64 + s*32 + (l>>4)*8];
  const int qlo = prow[tq0], qhi = prow[tq0+63];
  int sq[4];
  #pragma unroll
  for (int r=0;r<4;r++) sq[r] = prow[tq0 + w*16 + (l>>4)*4 + r];
  float lsum[4]; f32x4 ao[4];
  #pragma unroll
  for (int r=0;r<4;r++) lsum[r]=0.f;
  #pragma unroll
  for (int d=0;d<4;d++){ f32x4 z={0.f,0.f,0.f,0.f}; ao[d]=z; }
  const int nk = L/64;
  // ---- active-tile bitmask (uniform): wave 0 ballots over segment ranges
  bool act = false;
  if (tid < 64 && tid < nk){
    int tk0 = (tid*64)&511;
    act = (prow[tk0+63] >= qlo) && (prow[tk0] <= qhi);
  }
  unsigned long long bm = __ballot(act);
  if (tid==0) amask_s = bm;
  __syncthreads();
  unsigned long long rem = amask_s;   // non-empty: diagonal tile always active
  int t = (int)(__ffsll((unsigned long long)rem)-1); rem &= rem-1;
  // staging geometry: slot = it*256+tid; row=slot>>3; c16=slot&7.
  // pre-swizzled source column sc = c16 ^ (row&7); LDS stays linear.
  const int srow0 = tid>>3, sc16 = tid&7;
  while (true){
    const int k0 = t*64;
    __syncthreads();   // all waves done reading previous tile's K/V
    #pragma unroll
    for (int it=0; it<2; ++it){
      int row = it*32 + srow0;
      int sc = sc16 ^ (row&7);
      async_cp16(&K[base + (size_t)(k0+row)*64 + sc*8],        &Kl[(it*256+tid)*8]);
      async_cp16(&Vt[base + (size_t)row*(size_t)L + k0 + sc*8], &Vl[(it*256+tid)*8]);
    }
    __syncthreads();   // drains vmcnt: staged data visible to all waves
    // ---- compute current tile from LDS
    const int tk0 = (t*64) & 511;
    int skv[4];
    #pragma unroll
    for (int kb=0;kb<4;kb++) skv[kb] = prow[tk0 + kb*16 + (l&15)];
    // ---- QK^T
    f32x4 s4[4];
    #pragma unroll
    for (int kb=0;kb<4;kb++){
      const int krow = kb*16 + (l&15);
      f32x4 a = {0.f,0.f,0.f,0.f};
      #pragma unroll
      for (int s=0;s<2;s++){
        int boff = krow*128 + ((s*64 + (l>>4)*16) ^ ((krow&7)<<4));
        short8 kf = *(const short8*)((const char*)&Kl[0] + boff);
        a = __builtin_amdgcn_mfma_f32_16x16x32_bf16(qf[s], kf, a, 0,0,0);
      }
      s4[kb] = a;
    }
    // ---- mask + direct exp + P relayout (cvt_pk pairs)
    #pragma unroll
    for (int kb=0;kb<4;kb++){
      float p0 = (skv[kb] == sq[0]) ? __expf(s4[kb][0]*0.125f) : 0.f;
      float p1 = (skv[kb] == sq[1]) ? __expf(s4[kb][1]*0.125f) : 0.f;
      float p2 = (skv[kb] == sq[2]) ? __expf(s4[kb][2]*0.125f) : 0.f;
      float p3 = (skv[kb] == sq[3]) ? __expf(s4[kb][3]*0.125f) : 0.f;
      lsum[0]+=p0; lsum[1]+=p1; lsum[2]+=p2; lsum[3]+=p3;
      unsigned int u01 = cvt_pk_bf16(p0, p1);
      unsigned int u23 = cvt_pk_bf16(p2, p3);
      int prw0 = (l>>4)*4;
      Pl[w][(prw0+0)*64 + (((kb*32 + (l&15)*2) ^ (((prw0+0)&7)<<4))>>1)] = (u16)u01;
      Pl[w][(prw0+1)*64 + (((kb*32 + (l&15)*2) ^ (((prw0+1)&7)<<4))>>1)] = (u16)(u01>>16);
      Pl[w][(prw0+2)*64 + (((kb*32 + (l&15)*2) ^ (((prw0+2)&7)<<4))>>1)] = (u16)u23;
      Pl[w][(prw0+3)*64 + (((kb*32 + (l&15)*2) ^ (((prw0+3)&7)<<4))>>1)] = (u16)(u23>>16);
    }
    short8 pa[2];
    #pragma unroll
    for (int s=0;s<2;s++)
      pa[s] = *(const short8*)&Pl[w][(l&15)*64 + (((s*64 + (l>>4)*16) ^ (((l&15)&7)<<4))>>1)];
    // ---- PV
    #pragma unroll
    for (int d=0;d<4;d++){
      const int vrow = d*16 + (l&15);
      #pragma unroll
      for (int s=0;s<2;s++){
        int boff = vrow*128 + ((s*64 + (l>>4)*16) ^ ((vrow&7)<<4));
        short8 vf = *(const short8*)((const char*)&Vl[0] + boff);
        ao[d] = __builtin_amdgcn_mfma_f32_16x16x32_bf16(pa[s], vf, ao[d], 0,0,0);
      }
    }
    if (!rem) break;
    t = (int)(__ffsll((unsigned long long)rem)-1); rem &= rem-1;
  }
  // ---- final row-sum reduce + coalesced epilogue through Pl
  #pragma unroll
  for (int r=0;r<4;r++){
    #pragma unroll
    for (int m=1;m<=8;m<<=1) lsum[r] += __shfl_xor(lsum[r], m, 64);
    lsum[r] = 1.0f / lsum[r];
  }
  #pragma unroll
  for (int d=0;d<4;d++){
    unsigned int u01 = cvt_pk_bf16(ao[d][0]*lsum[0], ao[d][1]*lsum[1]);
    unsigned int u23 = cvt_pk_bf16(ao[d][2]*lsum[2], ao[d][3]*lsum[3]);
    int prw0 = (l>>4)*4, col = d*16 + (l&15);
    Pl[w][(prw0+0)*64 + col] = (u16)u01;
    Pl[w][(prw0+1)*64 + col] = (u16)(u01>>16);
    Pl[w][(prw0+2)*64 + col] = (u16)u23;
    Pl[w][(prw0+3)*64 + col] = (u16)(u23>>16);
  }
  __builtin_amdgcn_s_waitcnt(0);  // wave-private Pl slice: order writes->reads
  {
    int r16 = l&15, cchunk = (l>>4)*16;
    uint4 v0 = *(const uint4*)&Pl[w][r16*64 + cchunk];
    uint4 v1 = *(const uint4*)&Pl[w][r16*64 + cchunk + 8];
    size_t orow = (size_t)(orow0 + q0 + w*16 + r16)*1536 + ocol + cchunk;
    *(uint4*)&Out[orow]     = v0;
    *(uint4*)&Out[orow + 8] = v1;
  }
}

extern "C" void kernel_launch(void* const* d_in, const int* in_sizes, int n_in,
                              void* d_out, int out_size, void* d_ws, size_t ws_size,
                              hipStream_t stream) {
  const float* x      = (const float*)d_in[0];
  const int*   patch  = (const int*)d_in[1];
  const float* sincos = (const float*)d_in[2];
  const float* ln1s   = (const float*)d_in[3];
  const float* wqkv   = (const float*)d_in[4];
  const float* aq     = (const float*)d_in[5];
  const float* ak     = (const float*)d_in[6];
  const float* aqs    = (const float*)d_in[7];
  const float* aks    = (const float*)d_in[8];
  const float* wout   = (const float*)d_in[9];
  const float* bout   = (const float*)d_in[10];
  const float* ls1    = (const float*)d_in[11];
  const float* ln2s   = (const float*)d_in[12];
  const float* ln2b   = (const float*)d_in[13];
  const float* wm1    = (const float*)d_in[14];
  const float* bm1    = (const float*)d_in[15];
  const float* wm2    = (const float*)d_in[16];
  const float* bm2    = (const float*)d_in[17];
  const float* ls2    = (const float*)d_in[18];
  float* out = (float*)d_out;

  char* ws = (char*)d_ws;
  size_t off = 0;
  auto alloc = [&](size_t bytes)->void*{ void* p = ws + off; off += (bytes + 255) & ~(size_t)255; return p; };
  u16*  wqkvT = (u16*)alloc(4608ull*768*2);
  u16*  woutT = (u16*)alloc(768ull*1536*2);
  u16*  wm1T  = (u16*)alloc(3072ull*768*2);
  u16*  wm2T  = (u16*)alloc(768ull*3072*2);
  u16*  xin   = (u16*)alloc(4096ull*768*2);
  u16*  qkvb  = (u16*)alloc(4096ull*4608*2);   // bf16 qkv; ALSO aliased by split-K partials P
  u16*  qg    = (u16*)alloc(3145728ull*2);     // (P spans qkvb+qg+kg = 50,331,648 B exactly)
  u16*  kg    = (u16*)alloc(3145728ull*2);
  u16*  vg    = (u16*)alloc(3145728ull*2);     // transposed [2][12][64][2048]
  u16*  qsg   = (u16*)alloc(3145728ull*2);
  u16*  ksg   = (u16*)alloc(3145728ull*2);
  u16*  vsg   = (u16*)alloc(3145728ull*2);     // transposed [8][12][64][512]
  u16*  cat   = (u16*)alloc(4096ull*1536*2);
  float* x0   = (float*)alloc(4096ull*768*4);
  u16*  x1    = (u16*)alloc(4096ull*768*2);
  u16*  hbuf  = (u16*)alloc(4096ull*3072*2);
  float* P    = (float*)qkvb;                  // 4 x 4096 x 768 f32 partial planes

  dim3 b256(256);
  wtrans_k<<<dim3(144,24),b256,0,stream>>>(wqkv, wqkvT, 768, 4608);
  wtrans_k<<<dim3(24,48),b256,0,stream>>>(wout, woutT, 1536, 768);
  wtrans_k<<<dim3(96,24),b256,0,stream>>>(wm1, wm1T, 768, 3072);
  wtrans_k<<<dim3(24,96),b256,0,stream>>>(wm2, wm2T, 3072, 768);
  ln1_k<<<4096,b256,0,stream>>>(x, ln1s, xin);
  gemm_k<3,1><<<dim3(36,32),b256,0,stream>>>(xin, wqkvT, 4096, 4608, 768, nullptr, qkvb, nullptr);
  postproc2_k<<<768,b256,0,stream>>>(qkvb, sincos, aq, ak, aqs, aks, qg,kg,vg,qsg,ksg,vsg);
  attn7_k<<<1536,b256,0,stream>>>(qg,kg,vg, qsg,ksg,vsg, cat, patch);
  gemm_k<0,4><<<dim3(6,32,4),b256,0,stream>>>(cat, woutT, 4096, 768, 1536, P, nullptr, nullptr);
  redln_k<<<4096,b256,0,stream>>>(P, bout, ls1, x, ln2s, ln2b, x0, x1);
  gemm_k<2,1><<<dim3(24,32),b256,0,stream>>>(x1, wm1T, 4096, 3072, 768, nullptr, hbuf, bm1);
  gemm_k<0,4><<<dim3(6,32,4),b256,0,stream>>>(hbuf, wm2T, 4096, 768, 3072, P, nullptr, nullptr);
  red_k<<<3072,b256,0,stream>>>(P, bm2, ls2, x0, out);
}

// Round 12
// 228.696 us; speedup vs baseline: 1.2137x; 1.0886x over previous
//
#include <hip/hip_runtime.h>

#define DEVI __device__ __forceinline__

typedef __attribute__((ext_vector_type(8))) short short8;
typedef __attribute__((ext_vector_type(4))) float f32x4;
typedef unsigned short u16;

DEVI u16 f2bf(float f){
  unsigned int u = __float_as_uint(f);
  unsigned int r = (u + 0x7FFFu + ((u>>16)&1u)) >> 16;
  return (u16)r;
}
DEVI float bf2f(u16 h){ return __uint_as_float(((unsigned int)h)<<16); }

DEVI unsigned int cvt_pk_bf16(float a, float b){
  unsigned int r;
  asm("v_cvt_pk_bf16_f32 %0, %1, %2" : "=v"(r) : "v"(a), "v"(b));
  return r;   // lo = bf16(a), hi = bf16(b)
}

DEVI float gelu_f(float x){
  float x3 = x*x*x;
  float t = tanhf(0.7978845608028654f*(x + 0.044715f*x3));
  return 0.5f*x*(1.0f + t);
}

DEVI void async_cp16(const void* g, void* l){
  __builtin_amdgcn_global_load_lds(
      (const __attribute__((address_space(1))) unsigned int*)g,
      (__attribute__((address_space(3))) unsigned int*)l, 16, 0, 0);
}

// ---------------- merged weight transpose + bf16 convert (all 4 weights, 1 launch)
// w (K x N) f32 -> wt (N x K) bf16
DEVI void wtrans_body(const float* __restrict__ w, u16* __restrict__ wt,
                      int K, int N, int bx, int by, int tid){
  __shared__ float tile[32][33];
  int tn = bx*32, tk = by*32;
  int r = tid>>3, c4 = (tid&7)*4;
  float4 vv = *(const float4*)&w[(size_t)(tk+r)*N + tn + c4];
  tile[r][c4+0]=vv.x; tile[r][c4+1]=vv.y; tile[r][c4+2]=vv.z; tile[r][c4+3]=vv.w;
  __syncthreads();
  u16 o[4];
  #pragma unroll
  for (int j=0;j<4;j++) o[j] = f2bf(tile[c4+j][r]);
  unsigned long long pk = (unsigned long long)o[0] | ((unsigned long long)o[1]<<16)
                        | ((unsigned long long)o[2]<<32) | ((unsigned long long)o[3]<<48);
  *(unsigned long long*)&wt[(size_t)(tn+r)*K + tk + c4] = pk;
}

__global__ __launch_bounds__(256) void wtrans4_k(
    const float* __restrict__ w0, u16* __restrict__ o0,   // 768 x 4608
    const float* __restrict__ w1, u16* __restrict__ o1,   // 1536 x 768
    const float* __restrict__ w2, u16* __restrict__ o2,   // 768 x 3072
    const float* __restrict__ w3, u16* __restrict__ o3)   // 3072 x 768
{
  int bid = blockIdx.x, tid = threadIdx.x;
  if (bid < 3456){            wtrans_body(w0,o0, 768,4608, bid%144, bid/144, tid); }
  else if (bid < 4608){ int b=bid-3456; wtrans_body(w1,o1,1536, 768, b%24,  b/24,  tid); }
  else if (bid < 6912){ int b=bid-4608; wtrans_body(w2,o2, 768,3072, b%96,  b/96,  tid); }
  else               { int b=bid-6912; wtrans_body(w3,o3,3072, 768, b%24,  b/24,  tid); }
}

// ---------------- LN1: x f32 (4096x768) -> xin bf16
__global__ __launch_bounds__(256) void ln1_k(const float* __restrict__ x,
                                             const float* __restrict__ sc,
                                             u16* __restrict__ xin){
  int row = blockIdx.x, tid = threadIdx.x;
  const float* xr = x + (size_t)row*768;
  float v[3]; float s=0.f, ss=0.f;
  #pragma unroll
  for (int i=0;i<3;i++){ v[i]=xr[tid+i*256]; s+=v[i]; ss+=v[i]*v[i]; }
  #pragma unroll
  for (int m=1;m<=32;m<<=1){ s += __shfl_xor(s,m,64); ss += __shfl_xor(ss,m,64); }
  __shared__ float ls0[4], ls1_[4];
  int w = tid>>6;
  if ((tid&63)==0){ ls0[w]=s; ls1_[w]=ss; }
  __syncthreads();
  s = ls0[0]+ls0[1]+ls0[2]+ls0[3]; ss = ls1_[0]+ls1_[1]+ls1_[2]+ls1_[3];
  float mu = s*(1.f/768.f);
  float var = ss*(1.f/768.f) - mu*mu;
  float inv = rsqrtf(var + 1e-6f);
  #pragma unroll
  for (int i=0;i<3;i++){ int c=tid+i*256; xin[(size_t)row*768+c] = f2bf((v[i]-mu)*inv*sc[c]); }
}

// ---------------- GEMM v2: C(MxN) = A(MxK,bf16) * Bt(NxK,bf16)^T
// BK=64 (half the barriers of BK=32); LDS linear [128][64]u16 with the
// attn7-proven swizzle: global source chunk pre-XOR'd (c^(row&7)), fragment
// reads XOR the same involution -> bank conflicts at the b128 floor.
// EPI 0: f32 partial plane (split-K)   EPI 2: bf16(gelu(acc+bias))   EPI 3: plain bf16
template<int EPI, int SPLITK>
__global__ __launch_bounds__(256) void gemm_k(
    const u16* __restrict__ A, const u16* __restrict__ Bt,
    int M, int N, int K,
    float* __restrict__ Cf, u16* __restrict__ Cb,
    const float* __restrict__ bias)
{
  __shared__ __align__(16) u16 Al[128*64];
  __shared__ __align__(16) u16 Bl[128*64];
  const int tid = threadIdx.x, w = tid>>6, l = tid&63;
  const int m0 = blockIdx.y*128, n0 = blockIdx.x*128;
  const int Ksub = K/SPLITK;
  const int kc = (SPLITK>1) ? blockIdx.z : 0;
  const int kbase = kc*Ksub;
  const int wr = (w>>1)*64, wc = (w&1)*64;
  f32x4 acc[4][4];
  #pragma unroll
  for (int i=0;i<4;i++)
    #pragma unroll
    for (int j=0;j<4;j++){ f32x4 z={0.f,0.f,0.f,0.f}; acc[i][j]=z; }
  // staging geometry: slot = it*256+tid; row = slot>>3; chunk(dst) = tid&7;
  // source chunk = (tid&7) ^ (row&7)  (involution; LDS stays linear)
  const int srow0 = tid>>3, sc16 = tid&7;
  for (int k0=0; k0<Ksub; k0+=64){
    __syncthreads();
    #pragma unroll
    for (int it=0; it<4; ++it){
      int row = it*32 + srow0;
      int sc = sc16 ^ (row&7);
      async_cp16(A  + (size_t)(m0+row)*K + kbase + k0 + sc*8, &Al[(it*256+tid)*8]);
      async_cp16(Bt + (size_t)(n0+row)*K + kbase + k0 + sc*8, &Bl[(it*256+tid)*8]);
    }
    __syncthreads();
    #pragma unroll
    for (int ks=0; ks<2; ++ks){
      short8 af[4], bfr[4];
      #pragma unroll
      for (int mi=0;mi<4;++mi){
        int row = wr + mi*16 + (l&15);
        int boff = row*128 + (((l>>4)*16 + ks*64) ^ ((row&7)<<4));
        af[mi] = *(const short8*)((const char*)&Al[0] + boff);
      }
      #pragma unroll
      for (int ni=0;ni<4;++ni){
        int row = wc + ni*16 + (l&15);
        int boff = row*128 + (((l>>4)*16 + ks*64) ^ ((row&7)<<4));
        bfr[ni] = *(const short8*)((const char*)&Bl[0] + boff);
      }
      #pragma unroll
      for (int mi=0;mi<4;++mi)
        #pragma unroll
        for (int ni=0;ni<4;++ni)
          acc[mi][ni] = __builtin_amdgcn_mfma_f32_16x16x32_bf16(af[mi], bfr[ni], acc[mi][ni], 0,0,0);
    }
  }
  #pragma unroll
  for (int mi=0;mi<4;++mi){
    int rb = m0 + wr + mi*16 + ((l>>4)<<2);
    #pragma unroll
    for (int ni=0;ni<4;++ni){
      int col = n0 + wc + ni*16 + (l&15);
      #pragma unroll
      for (int r=0;r<4;r++){
        int row = rb + r;
        float v = acc[mi][ni][r];
        if (EPI==0)      Cf[((size_t)kc*M + row)*N + col] = v;
        else if (EPI==2) Cb[(size_t)row*N+col] = f2bf(gelu_f(v + bias[col]));
        else             Cb[(size_t)row*N+col] = f2bf(v);
      }
    }
  }
}

// ---------------- split-K reduce + bias/ls/resid + LN2 + gelu (out-proj path)
__global__ __launch_bounds__(256) void redln_k(
    const float* __restrict__ P, const float* __restrict__ bias,
    const float* __restrict__ lsc, const float* __restrict__ resid,
    const float* __restrict__ ln2sc, const float* __restrict__ ln2bi,
    float* __restrict__ x0, u16* __restrict__ x1)
{
  const size_t MN = 4096ull*768;
  int row = blockIdx.x, tid = threadIdx.x;
  float v[3]; float s=0.f, ss=0.f;
  #pragma unroll
  for (int i=0;i<3;i++){
    int c = tid + i*256;
    size_t idx = (size_t)row*768 + c;
    float acc = P[idx] + P[MN+idx] + P[2*MN+idx] + P[3*MN+idx];
    float y = lsc[c]*(acc + bias[c]) + resid[idx];
    x0[idx] = y;
    v[i] = y; s += y; ss += y*y;
  }
  #pragma unroll
  for (int m=1;m<=32;m<<=1){ s += __shfl_xor(s,m,64); ss += __shfl_xor(ss,m,64); }
  __shared__ float ls0[4], ls1_[4];
  int w = tid>>6;
  if ((tid&63)==0){ ls0[w]=s; ls1_[w]=ss; }
  __syncthreads();
  s = ls0[0]+ls0[1]+ls0[2]+ls0[3]; ss = ls1_[0]+ls1_[1]+ls1_[2]+ls1_[3];
  float mu = s*(1.f/768.f);
  float var = ss*(1.f/768.f) - mu*mu;
  float inv = rsqrtf(var + 1e-6f);
  #pragma unroll
  for (int i=0;i<3;i++){
    int c = tid + i*256;
    float y = (v[i]-mu)*inv*ln2sc[c] + ln2bi[c];
    x1[(size_t)row*768 + c] = f2bf(gelu_f(y));
  }
}

// ---------------- split-K reduce + bias/ls/resid (final output)
__global__ __launch_bounds__(256) void red_k(
    const float* __restrict__ P, const float* __restrict__ bias,
    const float* __restrict__ lsc, const float* __restrict__ resid,
    float* __restrict__ out)
{
  const size_t MN = 4096ull*768;
  size_t i = ((size_t)blockIdx.x*256 + threadIdx.x)*4;
  int c = (int)(i % 768);
  float4 a0 = *(const float4*)&P[i];
  float4 a1 = *(const float4*)&P[MN+i];
  float4 a2 = *(const float4*)&P[2*MN+i];
  float4 a3 = *(const float4*)&P[3*MN+i];
  float4 bi = *(const float4*)&bias[c];
  float4 ls = *(const float4*)&lsc[c];
  float4 rs = *(const float4*)&resid[i];
  float4 o;
  o.x = ls.x*(a0.x+a1.x+a2.x+a3.x + bi.x) + rs.x;
  o.y = ls.y*(a0.y+a1.y+a2.y+a3.y + bi.y) + rs.y;
  o.z = ls.z*(a0.z+a1.z+a2.z+a3.z + bi.z) + rs.z;
  o.w = ls.w*(a0.w+a1.w+a2.w+a3.w + bi.w) + rs.w;
  *(float4*)&out[i] = o;
}

// ---------------- qkv postprocess v2: tile kernel, rms+rope in-register,
// V transposed through padded LDS so ALL global writes are coalesced.
__global__ __launch_bounds__(256) void postproc2_k(
  const u16* __restrict__ qkv, const float* __restrict__ sincos,
  const float* __restrict__ aq, const float* __restrict__ ak,
  const float* __restrict__ aqs, const float* __restrict__ aks,
  u16* __restrict__ qg, u16* __restrict__ kg, u16* __restrict__ vg,
  u16* __restrict__ qsg, u16* __restrict__ ksg, u16* __restrict__ vsg)
{
  __shared__ u16 vt[2][64*66];   // [t][d] padded: row stride 66 u16 (132 B)
  const int bid = blockIdx.x;
  const int b = bid/384; int r0 = bid - b*384;
  const int v = r0/96;   int r1 = r0 - v*96;
  const int t6 = r1/12;  const int h = r1 - t6*12;
  const int T0 = t6*64;
  const int tid = threadIdx.x, w = tid>>6, l = tid&63;
  const int tq = l>>4, dq = l&15;
  const int m0 = b*2048 + v*512;
  const size_t gQbase = ((size_t)(b*12) + h)*2048 + v*512;
  const size_t sQbase = ((size_t)((v*2+b)*12) + h)*512;

  // ---- q / k / qs / ks: rms + rope, row-coalesced writes
  #pragma unroll
  for (int qi=0; qi<4; ++qi){
    const int tt = (qi<2) ? qi : qi+1;          // 0,1,3,4
    const float* al = (qi==0)?aq:(qi==1)?ak:(qi==2)?aqs:aks;
    float4 alv = *(const float4*)&al[h*64 + dq*4];
    u16* dst = (qi==0)?qg:(qi==1)?kg:(qi==2)?qsg:ksg;
    const size_t obase = (qi<2) ? gQbase : sQbase;
    #pragma unroll
    for (int it=0; it<4; ++it){
      const int t = T0 + w*16 + it*4 + tq;
      const u16* src = &qkv[(size_t)(m0+t)*4608 + tt*768 + h*64 + dq*4];
      ushort2 u01 = *(const ushort2*)src;
      ushort2 u23 = *(const ushort2*)(src+2);
      float x0=bf2f(u01.x), x1=bf2f(u01.y), x2=bf2f(u23.x), x3=bf2f(u23.y);
      float ss = x0*x0+x1*x1+x2*x2+x3*x3;
      #pragma unroll
      for (int mm=1;mm<=8;mm<<=1) ss += __shfl_xor(ss,mm,64);
      float rinv = rsqrtf(ss*(1.f/64.f) + 1e-5f);
      x0 *= alv.x*rinv; x1 *= alv.y*rinv; x2 *= alv.z*rinv; x3 *= alv.w*rinv;
      float4 cs01 = *(const float4*)&sincos[(size_t)(t*64 + dq*4)*2];
      float4 cs23 = *(const float4*)&sincos[(size_t)(t*64 + dq*4)*2 + 4];
      float y0 = x0*cs01.x - x1*cs01.y;
      float y1 = x1*cs01.z + x0*cs01.w;
      float y2 = x2*cs23.x - x3*cs23.y;
      float y3 = x3*cs23.z + x2*cs23.w;
      unsigned int lo = cvt_pk_bf16(y0, y1);
      unsigned int hi = cvt_pk_bf16(y2, y3);
      unsigned int* po = (unsigned int*)&dst[(obase + t)*64 + dq*4];
      po[0] = lo; po[1] = hi;
    }
  }

  // ---- v / vs: stage [t][d] tiles in LDS, write transposed [d][t] coalesced
  #pragma unroll
  for (int vi=0; vi<2; ++vi){
    const int tt = (vi==0) ? 2 : 5;
    #pragma unroll
    for (int it=0; it<4; ++it){
      const int t = T0 + w*16 + it*4 + tq;
      const int tl = w*16 + it*4 + tq;
      const u16* src = &qkv[(size_t)(m0+t)*4608 + tt*768 + h*64 + dq*4];
      ushort2 u01 = *(const ushort2*)src;
      ushort2 u23 = *(const ushort2*)(src+2);
      unsigned int* pl = (unsigned int*)&vt[vi][tl*66 + dq*4];
      pl[0] = (unsigned int)u01.x | ((unsigned int)u01.y<<16);
      pl[1] = (unsigned int)u23.x | ((unsigned int)u23.y<<16);
    }
  }
  __syncthreads();
  {
    const size_t vgb = (((size_t)(b*12) + h)*64)*2048 + v*512 + T0 + l;
    #pragma unroll
    for (int i=0;i<16;++i){
      int d = w*16 + i;
      vg[vgb + (size_t)d*2048] = vt[0][l*66 + d];
    }
    const size_t vsb = (((size_t)((v*2+b)*12) + h)*64)*512 + T0 + l;
    #pragma unroll
    for (int i=0;i<16;++i){
      int d = w*16 + i;
      vsg[vsb + (size_t)d*512] = vt[1][l*66 + d];
    }
  }
}

// ---------------- merged segment-masked flash attention, QBLK=64, 1536 blocks
// Q/K: [seq][h][L][64] bf16 ; Vt: [seq][h][64][L] bf16 ; Out bf16 [4096][1536]
// Direct exp (|s|<=8, rms-norm'd q/k). K/V staged via global_load_lds
// (no VGPR round-trip). LDS linear; XOR bank-swizzle applied by pre-swizzling
// the GLOBAL source column (c16 ^ (row&7), involution) -> read side unchanged.
__global__ __launch_bounds__(256) void attn7_k(
  const u16* __restrict__ Qg, const u16* __restrict__ Kg, const u16* __restrict__ Vtg,
  const u16* __restrict__ Qs, const u16* __restrict__ Ks, const u16* __restrict__ Vts,
  u16* __restrict__ Out, const int* __restrict__ pids)
{
  __shared__ __align__(16) u16 Kl[64*64];
  __shared__ __align__(16) u16 Vl[64*64];
  __shared__ __align__(16) u16 Pl[4][16*64];
  __shared__ unsigned long long amask_s;
  const int gid = blockIdx.x;
  // balanced XCD swizzle: each XCD gets 96 global + 96 shifted contiguous blocks
  const int xcd = gid & 7, idx = gid >> 3;
  const int lid = (idx < 96) ? xcd*96 + idx : 768 + xcd*96 + (idx - 96);
  const int tid = threadIdx.x, w = tid>>6, l = tid&63;
  const u16 *Q, *K, *Vt; const int* prow;
  int L, seq, h, qb, orow0, ocol;
  if (lid < 768){
    seq = lid/384; int rem2 = lid - seq*384; h = rem2>>5; qb = rem2&31;
    Q=Qg; K=Kg; Vt=Vtg; L=2048;
    prow = pids + seq*512; orow0 = seq*2048; ocol = h*64;
  } else {
    int g2 = lid - 768; seq = g2/96; int rem2 = g2 - seq*96; h = rem2>>3; qb = rem2&7;
    Q=Qs; K=Ks; Vt=Vts; L=512;
    prow = pids + (seq&1)*512; orow0 = (seq&1)*2048 + (seq>>1)*512; ocol = 768 + h*64;
  }
  const size_t base = ((size_t)(seq*12) + h)*(size_t)L*64;
  const int q0 = qb*64, tq0 = q0 & 511;
  short8 qf[2];
  const int qrow = q0 + w*16 + (l&15);
  #pragma unroll
  for (int s=0;s<2;s++) qf[s] = *(const short8*)&Q[base + (size_t)qrow*64 + s*32 + (l>>4)*8];
  const int qlo = prow[tq0], qhi = prow[tq0+63];
  int sq[4];
  #pragma unroll
  for (int r=0;r<4;r++) sq[r] = prow[tq0 + w*16 + (l>>4)*4 + r];
  float lsum[4]; f32x4 ao[4];
  #pragma unroll
  for (int r=0;r<4;r++) lsum[r]=0.f;
  #pragma unroll
  for (int d=0;d<4;d++){ f32x4 z={0.f,0.f,0.f,0.f}; ao[d]=z; }
  const int nk = L/64;
  // ---- active-tile bitmask (uniform): wave 0 ballots over segment ranges
  bool act = false;
  if (tid < 64 && tid < nk){
    int tk0 = (tid*64)&511;
    act = (prow[tk0+63] >= qlo) && (prow[tk0] <= qhi);
  }
  unsigned long long bm = __ballot(act);
  if (tid==0) amask_s = bm;
  __syncthreads();
  unsigned long long rem = amask_s;   // non-empty: diagonal tile always active
  int t = (int)(__ffsll((unsigned long long)rem)-1); rem &= rem-1;
  const int srow0 = tid>>3, sc16 = tid&7;
  while (true){
    const int k0 = t*64;
    __syncthreads();   // all waves done reading previous tile's K/V
    #pragma unroll
    for (int it=0; it<2; ++it){
      int row = it*32 + srow0;
      int sc = sc16 ^ (row&7);
      async_cp16(&K[base + (size_t)(k0+row)*64 + sc*8],        &Kl[(it*256+tid)*8]);
      async_cp16(&Vt[base + (size_t)row*(size_t)L + k0 + sc*8], &Vl[(it*256+tid)*8]);
    }
    __syncthreads();   // drains vmcnt: staged data visible to all waves
    // ---- compute current tile from LDS
    const int tk0 = (t*64) & 511;
    int skv[4];
    #pragma unroll
    for (int kb=0;kb<4;kb++) skv[kb] = prow[tk0 + kb*16 + (l&15)];
    // ---- QK^T
    f32x4 s4[4];
    #pragma unroll
    for (int kb=0;kb<4;kb++){
      const int krow = kb*16 + (l&15);
      f32x4 a = {0.f,0.f,0.f,0.f};
      #pragma unroll
      for (int s=0;s<2;s++){
        int boff = krow*128 + ((s*64 + (l>>4)*16) ^ ((krow&7)<<4));
        short8 kf = *(const short8*)((const char*)&Kl[0] + boff);
        a = __builtin_amdgcn_mfma_f32_16x16x32_bf16(qf[s], kf, a, 0,0,0);
      }
      s4[kb] = a;
    }
    // ---- mask + direct exp + P relayout (cvt_pk pairs)
    #pragma unroll
    for (int kb=0;kb<4;kb++){
      float p0 = (skv[kb] == sq[0]) ? __expf(s4[kb][0]*0.125f) : 0.f;
      float p1 = (skv[kb] == sq[1]) ? __expf(s4[kb][1]*0.125f) : 0.f;
      float p2 = (skv[kb] == sq[2]) ? __expf(s4[kb][2]*0.125f) : 0.f;
      float p3 = (skv[kb] == sq[3]) ? __expf(s4[kb][3]*0.125f) : 0.f;
      lsum[0]+=p0; lsum[1]+=p1; lsum[2]+=p2; lsum[3]+=p3;
      unsigned int u01 = cvt_pk_bf16(p0, p1);
      unsigned int u23 = cvt_pk_bf16(p2, p3);
      int prw0 = (l>>4)*4;
      Pl[w][(prw0+0)*64 + (((kb*32 + (l&15)*2) ^ (((prw0+0)&7)<<4))>>1)] = (u16)u01;
      Pl[w][(prw0+1)*64 + (((kb*32 + (l&15)*2) ^ (((prw0+1)&7)<<4))>>1)] = (u16)(u01>>16);
      Pl[w][(prw0+2)*64 + (((kb*32 + (l&15)*2) ^ (((prw0+2)&7)<<4))>>1)] = (u16)u23;
      Pl[w][(prw0+3)*64 + (((kb*32 + (l&15)*2) ^ (((prw0+3)&7)<<4))>>1)] = (u16)(u23>>16);
    }
    short8 pa[2];
    #pragma unroll
    for (int s=0;s<2;s++)
      pa[s] = *(const short8*)&Pl[w][(l&15)*64 + (((s*64 + (l>>4)*16) ^ (((l&15)&7)<<4))>>1)];
    // ---- PV
    #pragma unroll
    for (int d=0;d<4;d++){
      const int vrow = d*16 + (l&15);
      #pragma unroll
      for (int s=0;s<2;s++){
        int boff = vrow*128 + ((s*64 + (l>>4)*16) ^ ((vrow&7)<<4));
        short8 vf = *(const short8*)((const char*)&Vl[0] + boff);
        ao[d] = __builtin_amdgcn_mfma_f32_16x16x32_bf16(pa[s], vf, ao[d], 0,0,0);
      }
    }
    if (!rem) break;
    t = (int)(__ffsll((unsigned long long)rem)-1); rem &= rem-1;
  }
  // ---- final row-sum reduce + coalesced epilogue through Pl
  #pragma unroll
  for (int r=0;r<4;r++){
    #pragma unroll
    for (int m=1;m<=8;m<<=1) lsum[r] += __shfl_xor(lsum[r], m, 64);
    lsum[r] = 1.0f / lsum[r];
  }
  #pragma unroll
  for (int d=0;d<4;d++){
    unsigned int u01 = cvt_pk_bf16(ao[d][0]*lsum[0], ao[d][1]*lsum[1]);
    unsigned int u23 = cvt_pk_bf16(ao[d][2]*lsum[2], ao[d][3]*lsum[3]);
    int prw0 = (l>>4)*4, col = d*16 + (l&15);
    Pl[w][(prw0+0)*64 + col] = (u16)u01;
    Pl[w][(prw0+1)*64 + col] = (u16)(u01>>16);
    Pl[w][(prw0+2)*64 + col] = (u16)u23;
    Pl[w][(prw0+3)*64 + col] = (u16)(u23>>16);
  }
  __builtin_amdgcn_s_waitcnt(0);  // wave-private Pl slice: order writes->reads
  {
    int r16 = l&15, cchunk = (l>>4)*16;
    uint4 v0 = *(const uint4*)&Pl[w][r16*64 + cchunk];
    uint4 v1 = *(const uint4*)&Pl[w][r16*64 + cchunk + 8];
    size_t orow = (size_t)(orow0 + q0 + w*16 + r16)*1536 + ocol + cchunk;
    *(uint4*)&Out[orow]     = v0;
    *(uint4*)&Out[orow + 8] = v1;
  }
}

extern "C" void kernel_launch(void* const* d_in, const int* in_sizes, int n_in,
                              void* d_out, int out_size, void* d_ws, size_t ws_size,
                              hipStream_t stream) {
  const float* x      = (const float*)d_in[0];
  const int*   patch  = (const int*)d_in[1];
  const float* sincos = (const float*)d_in[2];
  const float* ln1s   = (const float*)d_in[3];
  const float* wqkv   = (const float*)d_in[4];
  const float* aq     = (const float*)d_in[5];
  const float* ak     = (const float*)d_in[6];
  const float* aqs    = (const float*)d_in[7];
  const float* aks    = (const float*)d_in[8];
  const float* wout   = (const float*)d_in[9];
  const float* bout   = (const float*)d_in[10];
  const float* ls1    = (const float*)d_in[11];
  const float* ln2s   = (const float*)d_in[12];
  const float* ln2b   = (const float*)d_in[13];
  const float* wm1    = (const float*)d_in[14];
  const float* bm1    = (const float*)d_in[15];
  const float* wm2    = (const float*)d_in[16];
  const float* bm2    = (const float*)d_in[17];
  const float* ls2    = (const float*)d_in[18];
  float* out = (float*)d_out;

  char* ws = (char*)d_ws;
  size_t off = 0;
  auto alloc = [&](size_t bytes)->void*{ void* p = ws + off; off += (bytes + 255) & ~(size_t)255; return p; };
  u16*  wqkvT = (u16*)alloc(4608ull*768*2);
  u16*  woutT = (u16*)alloc(768ull*1536*2);
  u16*  wm1T  = (u16*)alloc(3072ull*768*2);
  u16*  wm2T  = (u16*)alloc(768ull*3072*2);
  u16*  xin   = (u16*)alloc(4096ull*768*2);
  u16*  qkvb  = (u16*)alloc(4096ull*4608*2);   // bf16 qkv; ALSO aliased by split-K partials P
  u16*  qg    = (u16*)alloc(3145728ull*2);     // (P spans qkvb+qg+kg = 50,331,648 B exactly)
  u16*  kg    = (u16*)alloc(3145728ull*2);
  u16*  vg    = (u16*)alloc(3145728ull*2);     // transposed [2][12][64][2048]
  u16*  qsg   = (u16*)alloc(3145728ull*2);
  u16*  ksg   = (u16*)alloc(3145728ull*2);
  u16*  vsg   = (u16*)alloc(3145728ull*2);     // transposed [8][12][64][512]
  u16*  cat   = (u16*)alloc(4096ull*1536*2);
  float* x0   = (float*)alloc(4096ull*768*4);
  u16*  x1    = (u16*)alloc(4096ull*768*2);
  u16*  hbuf  = (u16*)alloc(4096ull*3072*2);
  float* P    = (float*)qkvb;                  // 4 x 4096 x 768 f32 partial planes

  dim3 b256(256);
  wtrans4_k<<<9216,b256,0,stream>>>(wqkv,wqkvT, wout,woutT, wm1,wm1T, wm2,wm2T);
  ln1_k<<<4096,b256,0,stream>>>(x, ln1s, xin);
  gemm_k<3,1><<<dim3(36,32),b256,0,stream>>>(xin, wqkvT, 4096, 4608, 768, nullptr, qkvb, nullptr);
  postproc2_k<<<768,b256,0,stream>>>(qkvb, sincos, aq, ak, aqs, aks, qg,kg,vg,qsg,ksg,vsg);
  attn7_k<<<1536,b256,0,stream>>>(qg,kg,vg, qsg,ksg,vsg, cat, patch);
  gemm_k<0,4><<<dim3(6,32,4),b256,0,stream>>>(cat, woutT, 4096, 768, 1536, P, nullptr, nullptr);
  redln_k<<<4096,b256,0,stream>>>(P, bout, ls1, x, ln2s, ln2b, x0, x1);
  gemm_k<2,1><<<dim3(24,32),b256,0,stream>>>(x1, wm1T, 4096, 3072, 768, nullptr, hbuf, bm1);
  gemm_k<0,4><<<dim3(6,32,4),b256,0,stream>>>(hbuf, wm2T, 4096, 768, 3072, P, nullptr, nullptr);
  red_k<<<3072,b256,0,stream>>>(P, bm2, ls2, x0, out);
}

// Round 13
// 203.141 us; speedup vs baseline: 1.3664x; 1.1258x over previous
//
#include <hip/hip_runtime.h>

#define DEVI __device__ __forceinline__

typedef __attribute__((ext_vector_type(8))) short short8;
typedef __attribute__((ext_vector_type(4))) float f32x4;
typedef unsigned short u16;

DEVI u16 f2bf(float f){
  unsigned int u = __float_as_uint(f);
  unsigned int r = (u + 0x7FFFu + ((u>>16)&1u)) >> 16;
  return (u16)r;
}
DEVI float bf2f(u16 h){ return __uint_as_float(((unsigned int)h)<<16); }

DEVI unsigned int cvt_pk_bf16(float a, float b){
  unsigned int r;
  asm("v_cvt_pk_bf16_f32 %0, %1, %2" : "=v"(r) : "v"(a), "v"(b));
  return r;   // lo = bf16(a), hi = bf16(b)
}

DEVI float gelu_f(float x){
  float x3 = x*x*x;
  float t = tanhf(0.7978845608028654f*(x + 0.044715f*x3));
  return 0.5f*x*(1.0f + t);
}

DEVI void async_cp16(const void* g, void* l){
  __builtin_amdgcn_global_load_lds(
      (const __attribute__((address_space(1))) unsigned int*)g,
      (__attribute__((address_space(3))) unsigned int*)l, 16, 0, 0);
}

// ---------------- merged weight transpose + bf16 convert (all 4 weights, 1 launch)
DEVI void wtrans_body(const float* __restrict__ w, u16* __restrict__ wt,
                      int K, int N, int bx, int by, int tid){
  __shared__ float tile[32][33];
  int tn = bx*32, tk = by*32;
  int r = tid>>3, c4 = (tid&7)*4;
  float4 vv = *(const float4*)&w[(size_t)(tk+r)*N + tn + c4];
  tile[r][c4+0]=vv.x; tile[r][c4+1]=vv.y; tile[r][c4+2]=vv.z; tile[r][c4+3]=vv.w;
  __syncthreads();
  u16 o[4];
  #pragma unroll
  for (int j=0;j<4;j++) o[j] = f2bf(tile[c4+j][r]);
  unsigned long long pk = (unsigned long long)o[0] | ((unsigned long long)o[1]<<16)
                        | ((unsigned long long)o[2]<<32) | ((unsigned long long)o[3]<<48);
  *(unsigned long long*)&wt[(size_t)(tn+r)*K + tk + c4] = pk;
}

__global__ __launch_bounds__(256) void wtrans4_k(
    const float* __restrict__ w0, u16* __restrict__ o0,   // 768 x 4608
    const float* __restrict__ w1, u16* __restrict__ o1,   // 1536 x 768
    const float* __restrict__ w2, u16* __restrict__ o2,   // 768 x 3072
    const float* __restrict__ w3, u16* __restrict__ o3)   // 3072 x 768
{
  int bid = blockIdx.x, tid = threadIdx.x;
  if (bid < 3456){            wtrans_body(w0,o0, 768,4608, bid%144, bid/144, tid); }
  else if (bid < 4608){ int b=bid-3456; wtrans_body(w1,o1,1536, 768, b%24,  b/24,  tid); }
  else if (bid < 6912){ int b=bid-4608; wtrans_body(w2,o2, 768,3072, b%96,  b/96,  tid); }
  else               { int b=bid-6912; wtrans_body(w3,o3,3072, 768, b%24,  b/24,  tid); }
}

// ---------------- LN1: x f32 (4096x768) -> xin bf16
__global__ __launch_bounds__(256) void ln1_k(const float* __restrict__ x,
                                             const float* __restrict__ sc,
                                             u16* __restrict__ xin){
  int row = blockIdx.x, tid = threadIdx.x;
  const float* xr = x + (size_t)row*768;
  float v[3]; float s=0.f, ss=0.f;
  #pragma unroll
  for (int i=0;i<3;i++){ v[i]=xr[tid+i*256]; s+=v[i]; ss+=v[i]*v[i]; }
  #pragma unroll
  for (int m=1;m<=32;m<<=1){ s += __shfl_xor(s,m,64); ss += __shfl_xor(ss,m,64); }
  __shared__ float ls0[4], ls1_[4];
  int w = tid>>6;
  if ((tid&63)==0){ ls0[w]=s; ls1_[w]=ss; }
  __syncthreads();
  s = ls0[0]+ls0[1]+ls0[2]+ls0[3]; ss = ls1_[0]+ls1_[1]+ls1_[2]+ls1_[3];
  float mu = s*(1.f/768.f);
  float var = ss*(1.f/768.f) - mu*mu;
  float inv = rsqrtf(var + 1e-6f);
  #pragma unroll
  for (int i=0;i<3;i++){ int c=tid+i*256; xin[(size_t)row*768+c] = f2bf((v[i]-mu)*inv*sc[c]); }
}

// ---------------- GEMM v3: C(MxN) = A(MxK,bf16) * Bt(NxK,bf16)^T
// BK=64, swizzled global_load_lds staging (linear LDS, pre-XOR'd source).
// SPLITK>1: 1D grid 768, XCD-grouped remap (xcd=id&7 owns 4 row-panels x 6
// cols x 4 k-slices -> A working set 3.1MB L2-resident per XCD); partials
// written as BF16 (halves partial traffic; consumers scale by ls=0.01 so
// bf16 partial rounding is ~1e-4 absolute in the output).
// EPI 0: bf16 partial plane   EPI 2: bf16(gelu(acc+bias))   EPI 3: plain bf16
template<int EPI, int SPLITK>
__global__ __launch_bounds__(256) void gemm_k(
    const u16* __restrict__ A, const u16* __restrict__ Bt,
    int M, int N, int K,
    u16* __restrict__ Cb, const float* __restrict__ bias)
{
  __shared__ __align__(16) u16 Al[128*64];
  __shared__ __align__(16) u16 Bl[128*64];
  const int tid = threadIdx.x, w = tid>>6, l = tid&63;
  int bx, by, kc;
  if (SPLITK>1){
    int id = blockIdx.x;
    int xcd = id&7, j = id>>3;
    bx = j%6; int rr = (j/6)&3; kc = j/24;
    by = xcd*4 + rr;
  } else { bx = blockIdx.x; by = blockIdx.y; kc = 0; }
  const int m0 = by*128, n0 = bx*128;
  const int Ksub = K/SPLITK;
  const int kbase = kc*Ksub;
  const int wr = (w>>1)*64, wc = (w&1)*64;
  f32x4 acc[4][4];
  #pragma unroll
  for (int i=0;i<4;i++)
    #pragma unroll
    for (int j2=0;j2<4;j2++){ f32x4 z={0.f,0.f,0.f,0.f}; acc[i][j2]=z; }
  const int srow0 = tid>>3, sc16 = tid&7;
  for (int k0=0; k0<Ksub; k0+=64){
    __syncthreads();
    #pragma unroll
    for (int it=0; it<4; ++it){
      int row = it*32 + srow0;
      int sc = sc16 ^ (row&7);
      async_cp16(A  + (size_t)(m0+row)*K + kbase + k0 + sc*8, &Al[(it*256+tid)*8]);
      async_cp16(Bt + (size_t)(n0+row)*K + kbase + k0 + sc*8, &Bl[(it*256+tid)*8]);
    }
    __syncthreads();
    #pragma unroll
    for (int ks=0; ks<2; ++ks){
      short8 af[4], bfr[4];
      #pragma unroll
      for (int mi=0;mi<4;++mi){
        int row = wr + mi*16 + (l&15);
        int boff = row*128 + (((l>>4)*16 + ks*64) ^ ((row&7)<<4));
        af[mi] = *(const short8*)((const char*)&Al[0] + boff);
      }
      #pragma unroll
      for (int ni=0;ni<4;++ni){
        int row = wc + ni*16 + (l&15);
        int boff = row*128 + (((l>>4)*16 + ks*64) ^ ((row&7)<<4));
        bfr[ni] = *(const short8*)((const char*)&Bl[0] + boff);
      }
      #pragma unroll
      for (int mi=0;mi<4;++mi)
        #pragma unroll
        for (int ni=0;ni<4;++ni)
          acc[mi][ni] = __builtin_amdgcn_mfma_f32_16x16x32_bf16(af[mi], bfr[ni], acc[mi][ni], 0,0,0);
    }
  }
  #pragma unroll
  for (int mi=0;mi<4;++mi){
    int rb = m0 + wr + mi*16 + ((l>>4)<<2);
    #pragma unroll
    for (int ni=0;ni<4;++ni){
      int col = n0 + wc + ni*16 + (l&15);
      #pragma unroll
      for (int r=0;r<4;r++){
        int row = rb + r;
        float v = acc[mi][ni][r];
        if (EPI==0)      Cb[((size_t)kc*M + row)*N + col] = f2bf(v);
        else if (EPI==2) Cb[(size_t)row*N+col] = f2bf(gelu_f(v + bias[col]));
        else             Cb[(size_t)row*N+col] = f2bf(v);
      }
    }
  }
}

// ---------------- split-K reduce (bf16 partials) + bias/ls/resid + LN2 + gelu
__global__ __launch_bounds__(256) void redln_k(
    const u16* __restrict__ P, const float* __restrict__ bias,
    const float* __restrict__ lsc, const float* __restrict__ resid,
    const float* __restrict__ ln2sc, const float* __restrict__ ln2bi,
    float* __restrict__ x0, u16* __restrict__ x1)
{
  const size_t MN = 4096ull*768;
  int row = blockIdx.x, tid = threadIdx.x;
  float v[3]; float s=0.f, ss=0.f;
  #pragma unroll
  for (int i=0;i<3;i++){
    int c = tid + i*256;
    size_t idx = (size_t)row*768 + c;
    float acc = bf2f(P[idx]) + bf2f(P[MN+idx]) + bf2f(P[2*MN+idx]) + bf2f(P[3*MN+idx]);
    float y = lsc[c]*(acc + bias[c]) + resid[idx];
    x0[idx] = y;
    v[i] = y; s += y; ss += y*y;
  }
  #pragma unroll
  for (int m=1;m<=32;m<<=1){ s += __shfl_xor(s,m,64); ss += __shfl_xor(ss,m,64); }
  __shared__ float ls0[4], ls1_[4];
  int w = tid>>6;
  if ((tid&63)==0){ ls0[w]=s; ls1_[w]=ss; }
  __syncthreads();
  s = ls0[0]+ls0[1]+ls0[2]+ls0[3]; ss = ls1_[0]+ls1_[1]+ls1_[2]+ls1_[3];
  float mu = s*(1.f/768.f);
  float var = ss*(1.f/768.f) - mu*mu;
  float inv = rsqrtf(var + 1e-6f);
  #pragma unroll
  for (int i=0;i<3;i++){
    int c = tid + i*256;
    float y = (v[i]-mu)*inv*ln2sc[c] + ln2bi[c];
    x1[(size_t)row*768 + c] = f2bf(gelu_f(y));
  }
}

// ---------------- split-K reduce (bf16 partials) + bias/ls/resid (final output)
__global__ __launch_bounds__(256) void red_k(
    const u16* __restrict__ P, const float* __restrict__ bias,
    const float* __restrict__ lsc, const float* __restrict__ resid,
    float* __restrict__ out)
{
  const size_t MN = 4096ull*768;
  size_t i = ((size_t)blockIdx.x*256 + threadIdx.x)*4;
  int c = (int)(i % 768);
  ushort4 a0 = *(const ushort4*)&P[i];
  ushort4 a1 = *(const ushort4*)&P[MN+i];
  ushort4 a2 = *(const ushort4*)&P[2*MN+i];
  ushort4 a3 = *(const ushort4*)&P[3*MN+i];
  float4 bi = *(const float4*)&bias[c];
  float4 ls = *(const float4*)&lsc[c];
  float4 rs = *(const float4*)&resid[i];
  float4 o;
  o.x = ls.x*(bf2f(a0.x)+bf2f(a1.x)+bf2f(a2.x)+bf2f(a3.x) + bi.x) + rs.x;
  o.y = ls.y*(bf2f(a0.y)+bf2f(a1.y)+bf2f(a2.y)+bf2f(a3.y) + bi.y) + rs.y;
  o.z = ls.z*(bf2f(a0.z)+bf2f(a1.z)+bf2f(a2.z)+bf2f(a3.z) + bi.z) + rs.z;
  o.w = ls.w*(bf2f(a0.w)+bf2f(a1.w)+bf2f(a2.w)+bf2f(a3.w) + bi.w) + rs.w;
  *(float4*)&out[i] = o;
}

// ---------------- qkv postprocess v2: tile kernel, rms+rope in-register,
// V transposed through padded LDS so ALL global writes are coalesced.
__global__ __launch_bounds__(256) void postproc2_k(
  const u16* __restrict__ qkv, const float* __restrict__ sincos,
  const float* __restrict__ aq, const float* __restrict__ ak,
  const float* __restrict__ aqs, const float* __restrict__ aks,
  u16* __restrict__ qg, u16* __restrict__ kg, u16* __restrict__ vg,
  u16* __restrict__ qsg, u16* __restrict__ ksg, u16* __restrict__ vsg)
{
  __shared__ u16 vt[2][64*66];   // [t][d] padded: row stride 66 u16 (132 B)
  const int bid = blockIdx.x;
  const int b = bid/384; int r0 = bid - b*384;
  const int v = r0/96;   int r1 = r0 - v*96;
  const int t6 = r1/12;  const int h = r1 - t6*12;
  const int T0 = t6*64;
  const int tid = threadIdx.x, w = tid>>6, l = tid&63;
  const int tq = l>>4, dq = l&15;
  const int m0 = b*2048 + v*512;
  const size_t gQbase = ((size_t)(b*12) + h)*2048 + v*512;
  const size_t sQbase = ((size_t)((v*2+b)*12) + h)*512;

  // ---- q / k / qs / ks: rms + rope, row-coalesced writes
  #pragma unroll
  for (int qi=0; qi<4; ++qi){
    const int tt = (qi<2) ? qi : qi+1;          // 0,1,3,4
    const float* al = (qi==0)?aq:(qi==1)?ak:(qi==2)?aqs:aks;
    float4 alv = *(const float4*)&al[h*64 + dq*4];
    u16* dst = (qi==0)?qg:(qi==1)?kg:(qi==2)?qsg:ksg;
    const size_t obase = (qi<2) ? gQbase : sQbase;
    #pragma unroll
    for (int it=0; it<4; ++it){
      const int t = T0 + w*16 + it*4 + tq;
      const u16* src = &qkv[(size_t)(m0+t)*4608 + tt*768 + h*64 + dq*4];
      ushort2 u01 = *(const ushort2*)src;
      ushort2 u23 = *(const ushort2*)(src+2);
      float x0=bf2f(u01.x), x1=bf2f(u01.y), x2=bf2f(u23.x), x3=bf2f(u23.y);
      float ss = x0*x0+x1*x1+x2*x2+x3*x3;
      #pragma unroll
      for (int mm=1;mm<=8;mm<<=1) ss += __shfl_xor(ss,mm,64);
      float rinv = rsqrtf(ss*(1.f/64.f) + 1e-5f);
      x0 *= alv.x*rinv; x1 *= alv.y*rinv; x2 *= alv.z*rinv; x3 *= alv.w*rinv;
      float4 cs01 = *(const float4*)&sincos[(size_t)(t*64 + dq*4)*2];
      float4 cs23 = *(const float4*)&sincos[(size_t)(t*64 + dq*4)*2 + 4];
      float y0 = x0*cs01.x - x1*cs01.y;
      float y1 = x1*cs01.z + x0*cs01.w;
      float y2 = x2*cs23.x - x3*cs23.y;
      float y3 = x3*cs23.z + x2*cs23.w;
      unsigned int lo = cvt_pk_bf16(y0, y1);
      unsigned int hi = cvt_pk_bf16(y2, y3);
      unsigned int* po = (unsigned int*)&dst[(obase + t)*64 + dq*4];
      po[0] = lo; po[1] = hi;
    }
  }

  // ---- v / vs: stage [t][d] tiles in LDS, write transposed [d][t] coalesced
  #pragma unroll
  for (int vi=0; vi<2; ++vi){
    const int tt = (vi==0) ? 2 : 5;
    #pragma unroll
    for (int it=0; it<4; ++it){
      const int t = T0 + w*16 + it*4 + tq;
      const int tl = w*16 + it*4 + tq;
      const u16* src = &qkv[(size_t)(m0+t)*4608 + tt*768 + h*64 + dq*4];
      ushort2 u01 = *(const ushort2*)src;
      ushort2 u23 = *(const ushort2*)(src+2);
      unsigned int* pl = (unsigned int*)&vt[vi][tl*66 + dq*4];
      pl[0] = (unsigned int)u01.x | ((unsigned int)u01.y<<16);
      pl[1] = (unsigned int)u23.x | ((unsigned int)u23.y<<16);
    }
  }
  __syncthreads();
  {
    const size_t vgb = (((size_t)(b*12) + h)*64)*2048 + v*512 + T0 + l;
    #pragma unroll
    for (int i=0;i<16;++i){
      int d = w*16 + i;
      vg[vgb + (size_t)d*2048] = vt[0][l*66 + d];
    }
    const size_t vsb = (((size_t)((v*2+b)*12) + h)*64)*512 + T0 + l;
    #pragma unroll
    for (int i=0;i<16;++i){
      int d = w*16 + i;
      vsg[vsb + (size_t)d*512] = vt[1][l*66 + d];
    }
  }
}

// ---------------- merged segment-masked flash attention, QBLK=64, 1536 blocks
__global__ __launch_bounds__(256) void attn7_k(
  const u16* __restrict__ Qg, const u16* __restrict__ Kg, const u16* __restrict__ Vtg,
  const u16* __restrict__ Qs, const u16* __restrict__ Ks, const u16* __restrict__ Vts,
  u16* __restrict__ Out, const int* __restrict__ pids)
{
  __shared__ __align__(16) u16 Kl[64*64];
  __shared__ __align__(16) u16 Vl[64*64];
  __shared__ __align__(16) u16 Pl[4][16*64];
  __shared__ unsigned long long amask_s;
  const int gid = blockIdx.x;
  const int xcd = gid & 7, idx = gid >> 3;
  const int lid = (idx < 96) ? xcd*96 + idx : 768 + xcd*96 + (idx - 96);
  const int tid = threadIdx.x, w = tid>>6, l = tid&63;
  const u16 *Q, *K, *Vt; const int* prow;
  int L, seq, h, qb, orow0, ocol;
  if (lid < 768){
    seq = lid/384; int rem2 = lid - seq*384; h = rem2>>5; qb = rem2&31;
    Q=Qg; K=Kg; Vt=Vtg; L=2048;
    prow = pids + seq*512; orow0 = seq*2048; ocol = h*64;
  } else {
    int g2 = lid - 768; seq = g2/96; int rem2 = g2 - seq*96; h = rem2>>3; qb = rem2&7;
    Q=Qs; K=Ks; Vt=Vts; L=512;
    prow = pids + (seq&1)*512; orow0 = (seq&1)*2048 + (seq>>1)*512; ocol = 768 + h*64;
  }
  const size_t base = ((size_t)(seq*12) + h)*(size_t)L*64;
  const int q0 = qb*64, tq0 = q0 & 511;
  short8 qf[2];
  const int qrow = q0 + w*16 + (l&15);
  #pragma unroll
  for (int s=0;s<2;s++) qf[s] = *(const short8*)&Q[base + (size_t)qrow*64 + s*32 + (l>>4)*8];
  const int qlo = prow[tq0], qhi = prow[tq0+63];
  int sq[4];
  #pragma unroll
  for (int r=0;r<4;r++) sq[r] = prow[tq0 + w*16 + (l>>4)*4 + r];
  float lsum[4]; f32x4 ao[4];
  #pragma unroll
  for (int r=0;r<4;r++) lsum[r]=0.f;
  #pragma unroll
  for (int d=0;d<4;d++){ f32x4 z={0.f,0.f,0.f,0.f}; ao[d]=z; }
  const int nk = L/64;
  bool act = false;
  if (tid < 64 && tid < nk){
    int tk0 = (tid*64)&511;
    act = (prow[tk0+63] >= qlo) && (prow[tk0] <= qhi);
  }
  unsigned long long bm = __ballot(act);
  if (tid==0) amask_s = bm;
  __syncthreads();
  unsigned long long rem = amask_s;
  int t = (int)(__ffsll((unsigned long long)rem)-1); rem &= rem-1;
  const int srow0 = tid>>3, sc16 = tid&7;
  while (true){
    const int k0 = t*64;
    __syncthreads();
    #pragma unroll
    for (int it=0; it<2; ++it){
      int row = it*32 + srow0;
      int sc = sc16 ^ (row&7);
      async_cp16(&K[base + (size_t)(k0+row)*64 + sc*8],        &Kl[(it*256+tid)*8]);
      async_cp16(&Vt[base + (size_t)row*(size_t)L + k0 + sc*8], &Vl[(it*256+tid)*8]);
    }
    __syncthreads();
    const int tk0 = (t*64) & 511;
    int skv[4];
    #pragma unroll
    for (int kb=0;kb<4;kb++) skv[kb] = prow[tk0 + kb*16 + (l&15)];
    f32x4 s4[4];
    #pragma unroll
    for (int kb=0;kb<4;kb++){
      const int krow = kb*16 + (l&15);
      f32x4 a = {0.f,0.f,0.f,0.f};
      #pragma unroll
      for (int s=0;s<2;s++){
        int boff = krow*128 + ((s*64 + (l>>4)*16) ^ ((krow&7)<<4));
        short8 kf = *(const short8*)((const char*)&Kl[0] + boff);
        a = __builtin_amdgcn_mfma_f32_16x16x32_bf16(qf[s], kf, a, 0,0,0);
      }
      s4[kb] = a;
    }
    #pragma unroll
    for (int kb=0;kb<4;kb++){
      float p0 = (skv[kb] == sq[0]) ? __expf(s4[kb][0]*0.125f) : 0.f;
      float p1 = (skv[kb] == sq[1]) ? __expf(s4[kb][1]*0.125f) : 0.f;
      float p2 = (skv[kb] == sq[2]) ? __expf(s4[kb][2]*0.125f) : 0.f;
      float p3 = (skv[kb] == sq[3]) ? __expf(s4[kb][3]*0.125f) : 0.f;
      lsum[0]+=p0; lsum[1]+=p1; lsum[2]+=p2; lsum[3]+=p3;
      unsigned int u01 = cvt_pk_bf16(p0, p1);
      unsigned int u23 = cvt_pk_bf16(p2, p3);
      int prw0 = (l>>4)*4;
      Pl[w][(prw0+0)*64 + (((kb*32 + (l&15)*2) ^ (((prw0+0)&7)<<4))>>1)] = (u16)u01;
      Pl[w][(prw0+1)*64 + (((kb*32 + (l&15)*2) ^ (((prw0+1)&7)<<4))>>1)] = (u16)(u01>>16);
      Pl[w][(prw0+2)*64 + (((kb*32 + (l&15)*2) ^ (((prw0+2)&7)<<4))>>1)] = (u16)u23;
      Pl[w][(prw0+3)*64 + (((kb*32 + (l&15)*2) ^ (((prw0+3)&7)<<4))>>1)] = (u16)(u23>>16);
    }
    short8 pa[2];
    #pragma unroll
    for (int s=0;s<2;s++)
      pa[s] = *(const short8*)&Pl[w][(l&15)*64 + (((s*64 + (l>>4)*16) ^ (((l&15)&7)<<4))>>1)];
    #pragma unroll
    for (int d=0;d<4;d++){
      const int vrow = d*16 + (l&15);
      #pragma unroll
      for (int s=0;s<2;s++){
        int boff = vrow*128 + ((s*64 + (l>>4)*16) ^ ((vrow&7)<<4));
        short8 vf = *(const short8*)((const char*)&Vl[0] + boff);
        ao[d] = __builtin_amdgcn_mfma_f32_16x16x32_bf16(pa[s], vf, ao[d], 0,0,0);
      }
    }
    if (!rem) break;
    t = (int)(__ffsll((unsigned long long)rem)-1); rem &= rem-1;
  }
  #pragma unroll
  for (int r=0;r<4;r++){
    #pragma unroll
    for (int m=1;m<=8;m<<=1) lsum[r] += __shfl_xor(lsum[r], m, 64);
    lsum[r] = 1.0f / lsum[r];
  }
  #pragma unroll
  for (int d=0;d<4;d++){
    unsigned int u01 = cvt_pk_bf16(ao[d][0]*lsum[0], ao[d][1]*lsum[1]);
    unsigned int u23 = cvt_pk_bf16(ao[d][2]*lsum[2], ao[d][3]*lsum[3]);
    int prw0 = (l>>4)*4, col = d*16 + (l&15);
    Pl[w][(prw0+0)*64 + col] = (u16)u01;
    Pl[w][(prw0+1)*64 + col] = (u16)(u01>>16);
    Pl[w][(prw0+2)*64 + col] = (u16)u23;
    Pl[w][(prw0+3)*64 + col] = (u16)(u23>>16);
  }
  __builtin_amdgcn_s_waitcnt(0);
  {
    int r16 = l&15, cchunk = (l>>4)*16;
    uint4 v0 = *(const uint4*)&Pl[w][r16*64 + cchunk];
    uint4 v1 = *(const uint4*)&Pl[w][r16*64 + cchunk + 8];
    size_t orow = (size_t)(orow0 + q0 + w*16 + r16)*1536 + ocol + cchunk;
    *(uint4*)&Out[orow]     = v0;
    *(uint4*)&Out[orow + 8] = v1;
  }
}

extern "C" void kernel_launch(void* const* d_in, const int* in_sizes, int n_in,
                              void* d_out, int out_size, void* d_ws, size_t ws_size,
                              hipStream_t stream) {
  const float* x      = (const float*)d_in[0];
  const int*   patch  = (const int*)d_in[1];
  const float* sincos = (const float*)d_in[2];
  const float* ln1s   = (const float*)d_in[3];
  const float* wqkv   = (const float*)d_in[4];
  const float* aq     = (const float*)d_in[5];
  const float* ak     = (const float*)d_in[6];
  const float* aqs    = (const float*)d_in[7];
  const float* aks    = (const float*)d_in[8];
  const float* wout   = (const float*)d_in[9];
  const float* bout   = (const float*)d_in[10];
  const float* ls1    = (const float*)d_in[11];
  const float* ln2s   = (const float*)d_in[12];
  const float* ln2b   = (const float*)d_in[13];
  const float* wm1    = (const float*)d_in[14];
  const float* bm1    = (const float*)d_in[15];
  const float* wm2    = (const float*)d_in[16];
  const float* bm2    = (const float*)d_in[17];
  const float* ls2    = (const float*)d_in[18];
  float* out = (float*)d_out;

  char* ws = (char*)d_ws;
  size_t off = 0;
  auto alloc = [&](size_t bytes)->void*{ void* p = ws + off; off += (bytes + 255) & ~(size_t)255; return p; };
  u16*  wqkvT = (u16*)alloc(4608ull*768*2);
  u16*  woutT = (u16*)alloc(768ull*1536*2);
  u16*  wm1T  = (u16*)alloc(3072ull*768*2);
  u16*  wm2T  = (u16*)alloc(768ull*3072*2);
  u16*  xin   = (u16*)alloc(4096ull*768*2);
  u16*  qkvb  = (u16*)alloc(4096ull*4608*2);   // bf16 qkv; ALSO aliased by bf16 split-K partials P
  u16*  qg    = (u16*)alloc(3145728ull*2);
  u16*  kg    = (u16*)alloc(3145728ull*2);
  u16*  vg    = (u16*)alloc(3145728ull*2);     // transposed [2][12][64][2048]
  u16*  qsg   = (u16*)alloc(3145728ull*2);
  u16*  ksg   = (u16*)alloc(3145728ull*2);
  u16*  vsg   = (u16*)alloc(3145728ull*2);     // transposed [8][12][64][512]
  u16*  cat   = (u16*)alloc(4096ull*1536*2);
  float* x0   = (float*)alloc(4096ull*768*4);
  u16*  x1    = (u16*)alloc(4096ull*768*2);
  u16*  hbuf  = (u16*)alloc(4096ull*3072*2);
  u16*  P     = qkvb;                          // 4 x 4096 x 768 bf16 partial planes (25.2MB < qkvb)

  dim3 b256(256);
  wtrans4_k<<<9216,b256,0,stream>>>(wqkv,wqkvT, wout,woutT, wm1,wm1T, wm2,wm2T);
  ln1_k<<<4096,b256,0,stream>>>(x, ln1s, xin);
  gemm_k<3,1><<<dim3(36,32),b256,0,stream>>>(xin, wqkvT, 4096, 4608, 768, qkvb, nullptr);
  postproc2_k<<<768,b256,0,stream>>>(qkvb, sincos, aq, ak, aqs, aks, qg,kg,vg,qsg,ksg,vsg);
  attn7_k<<<1536,b256,0,stream>>>(qg,kg,vg, qsg,ksg,vsg, cat, patch);
  gemm_k<0,4><<<768,b256,0,stream>>>(cat, woutT, 4096, 768, 1536, P, nullptr);
  redln_k<<<4096,b256,0,stream>>>(P, bout, ls1, x, ln2s, ln2b, x0, x1);
  gemm_k<2,1><<<dim3(24,32),b256,0,stream>>>(x1, wm1T, 4096, 3072, 768, hbuf, bm1);
  gemm_k<0,4><<<768,b256,0,stream>>>(hbuf, wm2T, 4096, 768, 3072, P, nullptr);
  red_k<<<3072,b256,0,stream>>>(P, bm2, ls2, x0, out);
}

// Round 14
// 188.633 us; speedup vs baseline: 1.4715x; 1.0769x over previous
//
#include <hip/hip_runtime.h>

#define DEVI __device__ __forceinline__

typedef __attribute__((ext_vector_type(8))) short short8;
typedef __attribute__((ext_vector_type(4))) float f32x4;
typedef unsigned short u16;

DEVI u16 f2bf(float f){
  unsigned int u = __float_as_uint(f);
  unsigned int r = (u + 0x7FFFu + ((u>>16)&1u)) >> 16;
  return (u16)r;
}
DEVI float bf2f(u16 h){ return __uint_as_float(((unsigned int)h)<<16); }

DEVI unsigned int cvt_pk_bf16(float a, float b){
  unsigned int r;
  asm("v_cvt_pk_bf16_f32 %0, %1, %2" : "=v"(r) : "v"(a), "v"(b));
  return r;   // lo = bf16(a), hi = bf16(b)
}

DEVI float gelu_f(float x){
  float x3 = x*x*x;
  float t = tanhf(0.7978845608028654f*(x + 0.044715f*x3));
  return 0.5f*x*(1.0f + t);
}

DEVI void async_cp16(const void* g, void* l){
  __builtin_amdgcn_global_load_lds(
      (const __attribute__((address_space(1))) unsigned int*)g,
      (__attribute__((address_space(3))) unsigned int*)l, 16, 0, 0);
}

// ---------------- prep: 4x weight transpose+convert AND ln1, one launch
DEVI void wtrans_body(const float* __restrict__ w, u16* __restrict__ wt,
                      int K, int N, int bx, int by, int tid){
  __shared__ float tile[32][33];
  int tn = bx*32, tk = by*32;
  int r = tid>>3, c4 = (tid&7)*4;
  float4 vv = *(const float4*)&w[(size_t)(tk+r)*N + tn + c4];
  tile[r][c4+0]=vv.x; tile[r][c4+1]=vv.y; tile[r][c4+2]=vv.z; tile[r][c4+3]=vv.w;
  __syncthreads();
  u16 o[4];
  #pragma unroll
  for (int j=0;j<4;j++) o[j] = f2bf(tile[c4+j][r]);
  unsigned long long pk = (unsigned long long)o[0] | ((unsigned long long)o[1]<<16)
                        | ((unsigned long long)o[2]<<32) | ((unsigned long long)o[3]<<48);
  *(unsigned long long*)&wt[(size_t)(tn+r)*K + tk + c4] = pk;
}

DEVI void ln1_body(const float* __restrict__ x, const float* __restrict__ sc,
                   u16* __restrict__ xin, int row, int tid){
  __shared__ float ls0[4], ls1_[4];
  const float* xr = x + (size_t)row*768;
  float v[3]; float s=0.f, ss=0.f;
  #pragma unroll
  for (int i=0;i<3;i++){ v[i]=xr[tid+i*256]; s+=v[i]; ss+=v[i]*v[i]; }
  #pragma unroll
  for (int m=1;m<=32;m<<=1){ s += __shfl_xor(s,m,64); ss += __shfl_xor(ss,m,64); }
  int w = tid>>6;
  if ((tid&63)==0){ ls0[w]=s; ls1_[w]=ss; }
  __syncthreads();
  s = ls0[0]+ls0[1]+ls0[2]+ls0[3]; ss = ls1_[0]+ls1_[1]+ls1_[2]+ls1_[3];
  float mu = s*(1.f/768.f);
  float var = ss*(1.f/768.f) - mu*mu;
  float inv = rsqrtf(var + 1e-6f);
  #pragma unroll
  for (int i=0;i<3;i++){ int c=tid+i*256; xin[(size_t)row*768+c] = f2bf((v[i]-mu)*inv*sc[c]); }
}

__global__ __launch_bounds__(256) void prep_k(
    const float* __restrict__ w0, u16* __restrict__ o0,   // 768 x 4608
    const float* __restrict__ w1, u16* __restrict__ o1,   // 1536 x 768
    const float* __restrict__ w2, u16* __restrict__ o2,   // 768 x 3072
    const float* __restrict__ w3, u16* __restrict__ o3,   // 3072 x 768
    const float* __restrict__ x,  const float* __restrict__ ln1s,
    u16* __restrict__ xin)
{
  int bid = blockIdx.x, tid = threadIdx.x;
  if (bid < 3456){            wtrans_body(w0,o0, 768,4608, bid%144, bid/144, tid); }
  else if (bid < 4608){ int b=bid-3456; wtrans_body(w1,o1,1536, 768, b%24,  b/24,  tid); }
  else if (bid < 6912){ int b=bid-4608; wtrans_body(w2,o2, 768,3072, b%96,  b/96,  tid); }
  else if (bid < 9216){ int b=bid-6912; wtrans_body(w3,o3,3072, 768, b%24,  b/24,  tid); }
  else                { ln1_body(x, ln1s, xin, bid-9216, tid); }
}

// ---------------- GEMM v4: all shapes compile-time (K, N template; M=4096).
// BK=64, swizzled global_load_lds staging (linear LDS, pre-XOR'd source).
// Full k-loop unroll: staging addrs become base+imm, ds_read offsets const.
// SPLITK>1: 1D grid 768, XCD-grouped remap; bf16 partial planes.
// EPI 0: bf16 partial plane   EPI 2: bf16(gelu(acc+bias))   EPI 3: plain bf16
template<int EPI, int SPLITK, int K, int N>
__global__ __launch_bounds__(256) void gemm_k(
    const u16* __restrict__ A, const u16* __restrict__ Bt,
    u16* __restrict__ Cb, const float* __restrict__ bias)
{
  constexpr int M = 4096;
  constexpr int Ksub = K/SPLITK;
  __shared__ __align__(16) u16 Al[128*64];
  __shared__ __align__(16) u16 Bl[128*64];
  const int tid = threadIdx.x, w = tid>>6, l = tid&63;
  int bx, by, kc;
  if (SPLITK>1){
    int id = blockIdx.x;
    int xcd = id&7, j = id>>3;
    bx = j%6; int rr = (j/6)&3; kc = j/24;
    by = xcd*4 + rr;
  } else { bx = blockIdx.x; by = blockIdx.y; kc = 0; }
  const int m0 = by*128, n0 = bx*128;
  const int kbase = kc*Ksub;
  const int wr = (w>>1)*64, wc = (w&1)*64;
  f32x4 acc[4][4];
  #pragma unroll
  for (int i=0;i<4;i++)
    #pragma unroll
    for (int j2=0;j2<4;j2++){ f32x4 z={0.f,0.f,0.f,0.f}; acc[i][j2]=z; }
  const int srow0 = tid>>3, sc16 = tid&7;
  #pragma unroll
  for (int k0=0; k0<Ksub; k0+=64){
    __syncthreads();
    #pragma unroll
    for (int it=0; it<4; ++it){
      int row = it*32 + srow0;
      int sc = sc16 ^ (row&7);
      async_cp16(A  + (size_t)(m0+row)*K + kbase + k0 + sc*8, &Al[(it*256+tid)*8]);
      async_cp16(Bt + (size_t)(n0+row)*K + kbase + k0 + sc*8, &Bl[(it*256+tid)*8]);
    }
    __syncthreads();
    #pragma unroll
    for (int ks=0; ks<2; ++ks){
      short8 af[4], bfr[4];
      #pragma unroll
      for (int mi=0;mi<4;++mi){
        int row = wr + mi*16 + (l&15);
        int boff = row*128 + (((l>>4)*16 + ks*64) ^ ((row&7)<<4));
        af[mi] = *(const short8*)((const char*)&Al[0] + boff);
      }
      #pragma unroll
      for (int ni=0;ni<4;++ni){
        int row = wc + ni*16 + (l&15);
        int boff = row*128 + (((l>>4)*16 + ks*64) ^ ((row&7)<<4));
        bfr[ni] = *(const short8*)((const char*)&Bl[0] + boff);
      }
      #pragma unroll
      for (int mi=0;mi<4;++mi)
        #pragma unroll
        for (int ni=0;ni<4;++ni)
          acc[mi][ni] = __builtin_amdgcn_mfma_f32_16x16x32_bf16(af[mi], bfr[ni], acc[mi][ni], 0,0,0);
    }
  }
  #pragma unroll
  for (int mi=0;mi<4;++mi){
    int rb = m0 + wr + mi*16 + ((l>>4)<<2);
    #pragma unroll
    for (int ni=0;ni<4;++ni){
      int col = n0 + wc + ni*16 + (l&15);
      #pragma unroll
      for (int r=0;r<4;r++){
        int row = rb + r;
        float v = acc[mi][ni][r];
        if (EPI==0)      Cb[((size_t)kc*M + row)*N + col] = f2bf(v);
        else if (EPI==2) Cb[(size_t)row*N+col] = f2bf(gelu_f(v + bias[col]));
        else             Cb[(size_t)row*N+col] = f2bf(v);
      }
    }
  }
}

// ---------------- split-K reduce (bf16 partials) + bias/ls/resid + LN2 + gelu
__global__ __launch_bounds__(256) void redln_k(
    const u16* __restrict__ P, const float* __restrict__ bias,
    const float* __restrict__ lsc, const float* __restrict__ resid,
    const float* __restrict__ ln2sc, const float* __restrict__ ln2bi,
    float* __restrict__ x0, u16* __restrict__ x1)
{
  const size_t MN = 4096ull*768;
  int row = blockIdx.x, tid = threadIdx.x;
  float v[3]; float s=0.f, ss=0.f;
  #pragma unroll
  for (int i=0;i<3;i++){
    int c = tid + i*256;
    size_t idx = (size_t)row*768 + c;
    float acc = bf2f(P[idx]) + bf2f(P[MN+idx]) + bf2f(P[2*MN+idx]) + bf2f(P[3*MN+idx]);
    float y = lsc[c]*(acc + bias[c]) + resid[idx];
    x0[idx] = y;
    v[i] = y; s += y; ss += y*y;
  }
  #pragma unroll
  for (int m=1;m<=32;m<<=1){ s += __shfl_xor(s,m,64); ss += __shfl_xor(ss,m,64); }
  __shared__ float ls0[4], ls1_[4];
  int w = tid>>6;
  if ((tid&63)==0){ ls0[w]=s; ls1_[w]=ss; }
  __syncthreads();
  s = ls0[0]+ls0[1]+ls0[2]+ls0[3]; ss = ls1_[0]+ls1_[1]+ls1_[2]+ls1_[3];
  float mu = s*(1.f/768.f);
  float var = ss*(1.f/768.f) - mu*mu;
  float inv = rsqrtf(var + 1e-6f);
  #pragma unroll
  for (int i=0;i<3;i++){
    int c = tid + i*256;
    float y = (v[i]-mu)*inv*ln2sc[c] + ln2bi[c];
    x1[(size_t)row*768 + c] = f2bf(gelu_f(y));
  }
}

// ---------------- split-K reduce (bf16 partials) + bias/ls/resid (final output)
__global__ __launch_bounds__(256) void red_k(
    const u16* __restrict__ P, const float* __restrict__ bias,
    const float* __restrict__ lsc, const float* __restrict__ resid,
    float* __restrict__ out)
{
  const size_t MN = 4096ull*768;
  size_t i = ((size_t)blockIdx.x*256 + threadIdx.x)*4;
  int c = (int)(i % 768);
  ushort4 a0 = *(const ushort4*)&P[i];
  ushort4 a1 = *(const ushort4*)&P[MN+i];
  ushort4 a2 = *(const ushort4*)&P[2*MN+i];
  ushort4 a3 = *(const ushort4*)&P[3*MN+i];
  float4 bi = *(const float4*)&bias[c];
  float4 ls = *(const float4*)&lsc[c];
  float4 rs = *(const float4*)&resid[i];
  float4 o;
  o.x = ls.x*(bf2f(a0.x)+bf2f(a1.x)+bf2f(a2.x)+bf2f(a3.x) + bi.x) + rs.x;
  o.y = ls.y*(bf2f(a0.y)+bf2f(a1.y)+bf2f(a2.y)+bf2f(a3.y) + bi.y) + rs.y;
  o.z = ls.z*(bf2f(a0.z)+bf2f(a1.z)+bf2f(a2.z)+bf2f(a3.z) + bi.z) + rs.z;
  o.w = ls.w*(bf2f(a0.w)+bf2f(a1.w)+bf2f(a2.w)+bf2f(a3.w) + bi.w) + rs.w;
  *(float4*)&out[i] = o;
}

// ---------------- qkv postprocess v2: tile kernel, rms+rope in-register,
// V transposed through padded LDS so ALL global writes are coalesced.
__global__ __launch_bounds__(256) void postproc2_k(
  const u16* __restrict__ qkv, const float* __restrict__ sincos,
  const float* __restrict__ aq, const float* __restrict__ ak,
  const float* __restrict__ aqs, const float* __restrict__ aks,
  u16* __restrict__ qg, u16* __restrict__ kg, u16* __restrict__ vg,
  u16* __restrict__ qsg, u16* __restrict__ ksg, u16* __restrict__ vsg)
{
  __shared__ u16 vt[2][64*66];   // [t][d] padded: row stride 66 u16 (132 B)
  const int bid = blockIdx.x;
  const int b = bid/384; int r0 = bid - b*384;
  const int v = r0/96;   int r1 = r0 - v*96;
  const int t6 = r1/12;  const int h = r1 - t6*12;
  const int T0 = t6*64;
  const int tid = threadIdx.x, w = tid>>6, l = tid&63;
  const int tq = l>>4, dq = l&15;
  const int m0 = b*2048 + v*512;
  const size_t gQbase = ((size_t)(b*12) + h)*2048 + v*512;
  const size_t sQbase = ((size_t)((v*2+b)*12) + h)*512;

  // ---- q / k / qs / ks: rms + rope, row-coalesced writes
  #pragma unroll
  for (int qi=0; qi<4; ++qi){
    const int tt = (qi<2) ? qi : qi+1;          // 0,1,3,4
    const float* al = (qi==0)?aq:(qi==1)?ak:(qi==2)?aqs:aks;
    float4 alv = *(const float4*)&al[h*64 + dq*4];
    u16* dst = (qi==0)?qg:(qi==1)?kg:(qi==2)?qsg:ksg;
    const size_t obase = (qi<2) ? gQbase : sQbase;
    #pragma unroll
    for (int it=0; it<4; ++it){
      const int t = T0 + w*16 + it*4 + tq;
      const u16* src = &qkv[(size_t)(m0+t)*4608 + tt*768 + h*64 + dq*4];
      ushort2 u01 = *(const ushort2*)src;
      ushort2 u23 = *(const ushort2*)(src+2);
      float x0=bf2f(u01.x), x1=bf2f(u01.y), x2=bf2f(u23.x), x3=bf2f(u23.y);
      float ss = x0*x0+x1*x1+x2*x2+x3*x3;
      #pragma unroll
      for (int mm=1;mm<=8;mm<<=1) ss += __shfl_xor(ss,mm,64);
      float rinv = rsqrtf(ss*(1.f/64.f) + 1e-5f);
      x0 *= alv.x*rinv; x1 *= alv.y*rinv; x2 *= alv.z*rinv; x3 *= alv.w*rinv;
      float4 cs01 = *(const float4*)&sincos[(size_t)(t*64 + dq*4)*2];
      float4 cs23 = *(const float4*)&sincos[(size_t)(t*64 + dq*4)*2 + 4];
      float y0 = x0*cs01.x - x1*cs01.y;
      float y1 = x1*cs01.z + x0*cs01.w;
      float y2 = x2*cs23.x - x3*cs23.y;
      float y3 = x3*cs23.z + x2*cs23.w;
      unsigned int lo = cvt_pk_bf16(y0, y1);
      unsigned int hi = cvt_pk_bf16(y2, y3);
      unsigned int* po = (unsigned int*)&dst[(obase + t)*64 + dq*4];
      po[0] = lo; po[1] = hi;
    }
  }

  // ---- v / vs: stage [t][d] tiles in LDS, write transposed [d][t] coalesced
  #pragma unroll
  for (int vi=0; vi<2; ++vi){
    const int tt = (vi==0) ? 2 : 5;
    #pragma unroll
    for (int it=0; it<4; ++it){
      const int t = T0 + w*16 + it*4 + tq;
      const int tl = w*16 + it*4 + tq;
      const u16* src = &qkv[(size_t)(m0+t)*4608 + tt*768 + h*64 + dq*4];
      ushort2 u01 = *(const ushort2*)src;
      ushort2 u23 = *(const ushort2*)(src+2);
      unsigned int* pl = (unsigned int*)&vt[vi][tl*66 + dq*4];
      pl[0] = (unsigned int)u01.x | ((unsigned int)u01.y<<16);
      pl[1] = (unsigned int)u23.x | ((unsigned int)u23.y<<16);
    }
  }
  __syncthreads();
  {
    const size_t vgb = (((size_t)(b*12) + h)*64)*2048 + v*512 + T0 + l;
    #pragma unroll
    for (int i=0;i<16;++i){
      int d = w*16 + i;
      vg[vgb + (size_t)d*2048] = vt[0][l*66 + d];
    }
    const size_t vsb = (((size_t)((v*2+b)*12) + h)*64)*512 + T0 + l;
    #pragma unroll
    for (int i=0;i<16;++i){
      int d = w*16 + i;
      vsg[vsb + (size_t)d*512] = vt[1][l*66 + d];
    }
  }
}

// ---------------- merged segment-masked flash attention, QBLK=64, 1536 blocks
__global__ __launch_bounds__(256) void attn7_k(
  const u16* __restrict__ Qg, const u16* __restrict__ Kg, const u16* __restrict__ Vtg,
  const u16* __restrict__ Qs, const u16* __restrict__ Ks, const u16* __restrict__ Vts,
  u16* __restrict__ Out, const int* __restrict__ pids)
{
  __shared__ __align__(16) u16 Kl[64*64];
  __shared__ __align__(16) u16 Vl[64*64];
  __shared__ __align__(16) u16 Pl[4][16*64];
  __shared__ unsigned long long amask_s;
  const int gid = blockIdx.x;
  const int xcd = gid & 7, idx = gid >> 3;
  const int lid = (idx < 96) ? xcd*96 + idx : 768 + xcd*96 + (idx - 96);
  const int tid = threadIdx.x, w = tid>>6, l = tid&63;
  const u16 *Q, *K, *Vt; const int* prow;
  int L, seq, h, qb, orow0, ocol;
  if (lid < 768){
    seq = lid/384; int rem2 = lid - seq*384; h = rem2>>5; qb = rem2&31;
    Q=Qg; K=Kg; Vt=Vtg; L=2048;
    prow = pids + seq*512; orow0 = seq*2048; ocol = h*64;
  } else {
    int g2 = lid - 768; seq = g2/96; int rem2 = g2 - seq*96; h = rem2>>3; qb = rem2&7;
    Q=Qs; K=Ks; Vt=Vts; L=512;
    prow = pids + (seq&1)*512; orow0 = (seq&1)*2048 + (seq>>1)*512; ocol = 768 + h*64;
  }
  const size_t base = ((size_t)(seq*12) + h)*(size_t)L*64;
  const int q0 = qb*64, tq0 = q0 & 511;
  short8 qf[2];
  const int qrow = q0 + w*16 + (l&15);
  #pragma unroll
  for (int s=0;s<2;s++) qf[s] = *(const short8*)&Q[base + (size_t)qrow*64 + s*32 + (l>>4)*8];
  const int qlo = prow[tq0], qhi = prow[tq0+63];
  int sq[4];
  #pragma unroll
  for (int r=0;r<4;r++) sq[r] = prow[tq0 + w*16 + (l>>4)*4 + r];
  float lsum[4]; f32x4 ao[4];
  #pragma unroll
  for (int r=0;r<4;r++) lsum[r]=0.f;
  #pragma unroll
  for (int d=0;d<4;d++){ f32x4 z={0.f,0.f,0.f,0.f}; ao[d]=z; }
  const int nk = L/64;
  bool act = false;
  if (tid < 64 && tid < nk){
    int tk0 = (tid*64)&511;
    act = (prow[tk0+63] >= qlo) && (prow[tk0] <= qhi);
  }
  unsigned long long bm = __ballot(act);
  if (tid==0) amask_s = bm;
  __syncthreads();
  unsigned long long rem = amask_s;
  int t = (int)(__ffsll((unsigned long long)rem)-1); rem &= rem-1;
  const int srow0 = tid>>3, sc16 = tid&7;
  while (true){
    const int k0 = t*64;
    __syncthreads();
    #pragma unroll
    for (int it=0; it<2; ++it){
      int row = it*32 + srow0;
      int sc = sc16 ^ (row&7);
      async_cp16(&K[base + (size_t)(k0+row)*64 + sc*8],        &Kl[(it*256+tid)*8]);
      async_cp16(&Vt[base + (size_t)row*(size_t)L + k0 + sc*8], &Vl[(it*256+tid)*8]);
    }
    __syncthreads();
    const int tk0 = (t*64) & 511;
    int skv[4];
    #pragma unroll
    for (int kb=0;kb<4;kb++) skv[kb] = prow[tk0 + kb*16 + (l&15)];
    f32x4 s4[4];
    #pragma unroll
    for (int kb=0;kb<4;kb++){
      const int krow = kb*16 + (l&15);
      f32x4 a = {0.f,0.f,0.f,0.f};
      #pragma unroll
      for (int s=0;s<2;s++){
        int boff = krow*128 + ((s*64 + (l>>4)*16) ^ ((krow&7)<<4));
        short8 kf = *(const short8*)((const char*)&Kl[0] + boff);
        a = __builtin_amdgcn_mfma_f32_16x16x32_bf16(qf[s], kf, a, 0,0,0);
      }
      s4[kb] = a;
    }
    #pragma unroll
    for (int kb=0;kb<4;kb++){
      float p0 = (skv[kb] == sq[0]) ? __expf(s4[kb][0]*0.125f) : 0.f;
      float p1 = (skv[kb] == sq[1]) ? __expf(s4[kb][1]*0.125f) : 0.f;
      float p2 = (skv[kb] == sq[2]) ? __expf(s4[kb][2]*0.125f) : 0.f;
      float p3 = (skv[kb] == sq[3]) ? __expf(s4[kb][3]*0.125f) : 0.f;
      lsum[0]+=p0; lsum[1]+=p1; lsum[2]+=p2; lsum[3]+=p3;
      unsigned int u01 = cvt_pk_bf16(p0, p1);
      unsigned int u23 = cvt_pk_bf16(p2, p3);
      int prw0 = (l>>4)*4;
      Pl[w][(prw0+0)*64 + (((kb*32 + (l&15)*2) ^ (((prw0+0)&7)<<4))>>1)] = (u16)u01;
      Pl[w][(prw0+1)*64 + (((kb*32 + (l&15)*2) ^ (((prw0+1)&7)<<4))>>1)] = (u16)(u01>>16);
      Pl[w][(prw0+2)*64 + (((kb*32 + (l&15)*2) ^ (((prw0+2)&7)<<4))>>1)] = (u16)u23;
      Pl[w][(prw0+3)*64 + (((kb*32 + (l&15)*2) ^ (((prw0+3)&7)<<4))>>1)] = (u16)(u23>>16);
    }
    short8 pa[2];
    #pragma unroll
    for (int s=0;s<2;s++)
      pa[s] = *(const short8*)&Pl[w][(l&15)*64 + (((s*64 + (l>>4)*16) ^ (((l&15)&7)<<4))>>1)];
    #pragma unroll
    for (int d=0;d<4;d++){
      const int vrow = d*16 + (l&15);
      #pragma unroll
      for (int s=0;s<2;s++){
        int boff = vrow*128 + ((s*64 + (l>>4)*16) ^ ((vrow&7)<<4));
        short8 vf = *(const short8*)((const char*)&Vl[0] + boff);
        ao[d] = __builtin_amdgcn_mfma_f32_16x16x32_bf16(pa[s], vf, ao[d], 0,0,0);
      }
    }
    if (!rem) break;
    t = (int)(__ffsll((unsigned long long)rem)-1); rem &= rem-1;
  }
  #pragma unroll
  for (int r=0;r<4;r++){
    #pragma unroll
    for (int m=1;m<=8;m<<=1) lsum[r] += __shfl_xor(lsum[r], m, 64);
    lsum[r] = 1.0f / lsum[r];
  }
  #pragma unroll
  for (int d=0;d<4;d++){
    unsigned int u01 = cvt_pk_bf16(ao[d][0]*lsum[0], ao[d][1]*lsum[1]);
    unsigned int u23 = cvt_pk_bf16(ao[d][2]*lsum[2], ao[d][3]*lsum[3]);
    int prw0 = (l>>4)*4, col = d*16 + (l&15);
    Pl[w][(prw0+0)*64 + col] = (u16)u01;
    Pl[w][(prw0+1)*64 + col] = (u16)(u01>>16);
    Pl[w][(prw0+2)*64 + col] = (u16)u23;
    Pl[w][(prw0+3)*64 + col] = (u16)(u23>>16);
  }
  __builtin_amdgcn_s_waitcnt(0);
  {
    int r16 = l&15, cchunk = (l>>4)*16;
    uint4 v0 = *(const uint4*)&Pl[w][r16*64 + cchunk];
    uint4 v1 = *(const uint4*)&Pl[w][r16*64 + cchunk + 8];
    size_t orow = (size_t)(orow0 + q0 + w*16 + r16)*1536 + ocol + cchunk;
    *(uint4*)&Out[orow]     = v0;
    *(uint4*)&Out[orow + 8] = v1;
  }
}

extern "C" void kernel_launch(void* const* d_in, const int* in_sizes, int n_in,
                              void* d_out, int out_size, void* d_ws, size_t ws_size,
                              hipStream_t stream) {
  const float* x      = (const float*)d_in[0];
  const int*   patch  = (const int*)d_in[1];
  const float* sincos = (const float*)d_in[2];
  const float* ln1s   = (const float*)d_in[3];
  const float* wqkv   = (const float*)d_in[4];
  const float* aq     = (const float*)d_in[5];
  const float* ak     = (const float*)d_in[6];
  const float* aqs    = (const float*)d_in[7];
  const float* aks    = (const float*)d_in[8];
  const float* wout   = (const float*)d_in[9];
  const float* bout   = (const float*)d_in[10];
  const float* ls1    = (const float*)d_in[11];
  const float* ln2s   = (const float*)d_in[12];
  const float* ln2b   = (const float*)d_in[13];
  const float* wm1    = (const float*)d_in[14];
  const float* bm1    = (const float*)d_in[15];
  const float* wm2    = (const float*)d_in[16];
  const float* bm2    = (const float*)d_in[17];
  const float* ls2    = (const float*)d_in[18];
  float* out = (float*)d_out;

  char* ws = (char*)d_ws;
  size_t off = 0;
  auto alloc = [&](size_t bytes)->void*{ void* p = ws + off; off += (bytes + 255) & ~(size_t)255; return p; };
  u16*  wqkvT = (u16*)alloc(4608ull*768*2);
  u16*  woutT = (u16*)alloc(768ull*1536*2);
  u16*  wm1T  = (u16*)alloc(3072ull*768*2);
  u16*  wm2T  = (u16*)alloc(768ull*3072*2);
  u16*  xin   = (u16*)alloc(4096ull*768*2);
  u16*  qkvb  = (u16*)alloc(4096ull*4608*2);   // bf16 qkv; ALSO aliased by bf16 split-K partials P
  u16*  qg    = (u16*)alloc(3145728ull*2);
  u16*  kg    = (u16*)alloc(3145728ull*2);
  u16*  vg    = (u16*)alloc(3145728ull*2);     // transposed [2][12][64][2048]
  u16*  qsg   = (u16*)alloc(3145728ull*2);
  u16*  ksg   = (u16*)alloc(3145728ull*2);
  u16*  vsg   = (u16*)alloc(3145728ull*2);     // transposed [8][12][64][512]
  u16*  cat   = (u16*)alloc(4096ull*1536*2);
  float* x0   = (float*)alloc(4096ull*768*4);
  u16*  x1    = (u16*)alloc(4096ull*768*2);
  u16*  hbuf  = (u16*)alloc(4096ull*3072*2);
  u16*  P     = qkvb;                          // 4 x 4096 x 768 bf16 partial planes

  dim3 b256(256);
  prep_k<<<13312,b256,0,stream>>>(wqkv,wqkvT, wout,woutT, wm1,wm1T, wm2,wm2T, x, ln1s, xin);
  gemm_k<3,1,768,4608><<<dim3(36,32),b256,0,stream>>>(xin, wqkvT, qkvb, nullptr);
  postproc2_k<<<768,b256,0,stream>>>(qkvb, sincos, aq, ak, aqs, aks, qg,kg,vg,qsg,ksg,vsg);
  attn7_k<<<1536,b256,0,stream>>>(qg,kg,vg, qsg,ksg,vsg, cat, patch);
  gemm_k<0,4,1536,768><<<768,b256,0,stream>>>(cat, woutT, P, nullptr);
  redln_k<<<4096,b256,0,stream>>>(P, bout, ls1, x, ln2s, ln2b, x0, x1);
  gemm_k<2,1,768,3072><<<dim3(24,32),b256,0,stream>>>(x1, wm1T, hbuf, bm1);
  gemm_k<0,4,3072,768><<<768,b256,0,stream>>>(hbuf, wm2T, P, nullptr);
  red_k<<<3072,b256,0,stream>>>(P, bm2, ls2, x0, out);
}